// Round 1
// baseline (3348.955 us; speedup 1.0000x reference)
//
#include <hip/hip_runtime.h>
#include <hip/hip_bf16.h>
#include <cstdint>
#include <cstddef>

#define SEQ_N 2048
#define DIM   1024
#define NHEAD 16
#define DH    64

// ---------------------------------------------------------------------------
// Generic fp32 GEMM: C[M,N] = A[M,K] @ B[K,N] + bias[N]
// 64x64 block tile, 16x16 threads, 4x4 per thread, BK=16.
// All problem dims are multiples of tile dims -> no bounds checks.
// ---------------------------------------------------------------------------
__global__ __launch_bounds__(256) void gemm_bias_kernel(
    const float* __restrict__ A, const float* __restrict__ B,
    const float* __restrict__ bias, float* __restrict__ C,
    int M, int N, int K)
{
    __shared__ float As[16][68];   // As[k][m_local], pad 68 -> float4-aligned rows
    __shared__ float Bs[16][68];   // Bs[k][n_local]

    const int tx = threadIdx.x & 15;   // n direction
    const int ty = threadIdx.x >> 4;   // m direction
    const int m0 = blockIdx.y * 64;
    const int n0 = blockIdx.x * 64;

    float acc[4][4] = {};

    for (int k0 = 0; k0 < K; k0 += 16) {
        // Stage A tile (64 rows x 16 k), stored transposed As[k][m]
        #pragma unroll
        for (int t = 0; t < 4; ++t) {
            int idx = threadIdx.x + t * 256;       // 0..1023
            int r = idx >> 4, c = idx & 15;        // A[m0+r][k0+c]
            As[c][r] = A[(size_t)(m0 + r) * K + k0 + c];
        }
        // Stage B tile (16 k x 64 n)
        #pragma unroll
        for (int t = 0; t < 4; ++t) {
            int idx = threadIdx.x + t * 256;
            int r = idx >> 6, c = idx & 63;        // B[k0+r][n0+c]
            Bs[r][c] = B[(size_t)(k0 + r) * N + n0 + c];
        }
        __syncthreads();

        #pragma unroll
        for (int k = 0; k < 16; ++k) {
            float4 av = *(const float4*)&As[k][ty << 2];
            float4 bv = *(const float4*)&Bs[k][tx << 2];
            float a[4] = {av.x, av.y, av.z, av.w};
            float b[4] = {bv.x, bv.y, bv.z, bv.w};
            #pragma unroll
            for (int ii = 0; ii < 4; ++ii)
                #pragma unroll
                for (int jj = 0; jj < 4; ++jj)
                    acc[ii][jj] = fmaf(a[ii], b[jj], acc[ii][jj]);
        }
        __syncthreads();
    }

    float4 bb = *(const float4*)&bias[n0 + (tx << 2)];
    const float badd[4] = {bb.x, bb.y, bb.z, bb.w};
    #pragma unroll
    for (int ii = 0; ii < 4; ++ii) {
        int m = m0 + (ty << 2) + ii;
        float4 o;
        o.x = acc[ii][0] + badd[0];
        o.y = acc[ii][1] + badd[1];
        o.z = acc[ii][2] + badd[2];
        o.w = acc[ii][3] + badd[3];
        *(float4*)&C[(size_t)m * N + n0 + (tx << 2)] = o;
    }
}

// ---------------------------------------------------------------------------
// Flash-style causal attention with Transformer-XL relative position bias.
//
// For j <= i:  score[i,j] = scale * ( q_i . k_j  +  q_i . p[n-1-(i-j)] )
// (rel_shift identity; j > i is causally masked.)
//
// Block = 256 threads = 4 waves; wave w handles query row i = i0 + w.
// Lane l handles key j = j0 + l within each 64-wide key tile.
// K/V tiles and the 67-row contiguous p-band are staged in LDS per block.
// Online softmax (m, l running) per wave; lane l accumulates out[d = l].
// ---------------------------------------------------------------------------
__global__ __launch_bounds__(256) void attn_kernel(
    const float* __restrict__ qb,   // (b, n, DIM)  head h at column h*DH
    const float* __restrict__ kvb,  // (b, n, 2*DIM) k = [:DIM], v = [DIM:]
    const float* __restrict__ pb,   // (n, DH)
    float* __restrict__ ob)         // (b, n, DIM)  attention output (pre-Wo)
{
    const int bh   = blockIdx.y;          // 0..31
    const int bi   = bh >> 4;             // batch
    const int hh   = bh & 15;             // head
    const int i0   = blockIdx.x << 2;     // first query row of block
    const int wave = threadIdx.x >> 6;
    const int lane = threadIdx.x & 63;
    const int i    = i0 + wave;           // this wave's query row

    __shared__ float ks[64][65];
    __shared__ float vs[64][65];
    __shared__ float ps[68][65];          // p band: rows base_m .. base_m+67
    __shared__ float qs[4][64];

    qs[wave][lane] =
        qb[((size_t)bi * SEQ_N + i0 + wave) * DIM + hh * DH + lane];

    float m_run = -1e30f;
    float l_run = 0.0f;
    float o_acc = 0.0f;                   // out[d = lane]

    const int jmax   = i0 + 3;
    const int ntiles = (jmax >> 6) + 1;

    for (int jt = 0; jt < ntiles; ++jt) {
        const int j0 = jt << 6;
        __syncthreads();   // previous tile consumed (and qs visible on jt=0)

        // Stage K and V tiles (coalesced rows of 64 floats)
        for (int idx = threadIdx.x; idx < 64 * 64; idx += 256) {
            int r = idx >> 6, c = idx & 63;
            const float* kvrow =
                kvb + ((size_t)bi * SEQ_N + j0 + r) * (2 * DIM) + hh * DH;
            ks[r][c] = kvrow[c];
            vs[r][c] = kvrow[DIM + c];
        }
        // Stage p band: rows m = base_m + r ; clamp rows >= n to 0 (masked)
        const int base_m = SEQ_N - 1 - jmax + j0;   // >= 0 always
        for (int idx = threadIdx.x; idx < 68 * 64; idx += 256) {
            int r = idx >> 6, c = idx & 63;
            int m = base_m + r;
            ps[r][c] = (m < SEQ_N) ? pb[(size_t)m * DH + c] : 0.0f;
        }
        __syncthreads();

        // Scores for j = j0 + lane
        const int j = j0 + lane;
        float s;
        if (j <= i) {
            float acc1 = 0.0f, acc2 = 0.0f;
            const int pr = lane + 3 - wave;     // ps row: m = n-1-i+j
            #pragma unroll 16
            for (int d0 = 0; d0 < 64; ++d0) {
                const float qd = qs[wave][d0];
                acc1 = fmaf(qd, ks[lane][d0], acc1);
                acc2 = fmaf(qd, ps[pr][d0], acc2);
            }
            s = (acc1 + acc2) * 0.125f;         // scale = d^-0.5 = 1/8
        } else {
            s = -1e30f;                          // causal mask (matches ref NEG_INF)
        }

        // Online softmax update (wave-uniform m_run / l_run)
        float tmax = s;
        #pragma unroll
        for (int off = 32; off > 0; off >>= 1)
            tmax = fmaxf(tmax, __shfl_xor(tmax, off));
        const float m_new = fmaxf(m_run, tmax);

        const float pl = __expf(s - m_new);      // masked lanes -> exp(-huge) = 0
        float tsum = pl;
        #pragma unroll
        for (int off = 32; off > 0; off >>= 1)
            tsum += __shfl_xor(tsum, off);

        const float alpha = __expf(m_run - m_new);  // first tile: exp(-inf) = 0
        l_run = l_run * alpha + tsum;
        o_acc *= alpha;

        // PV: o[d=lane] += sum_j p_j * v[j][d]
        #pragma unroll
        for (int jj = 0; jj < 64; ++jj) {
            const float pj = __shfl(pl, jj);
            o_acc = fmaf(pj, vs[jj][lane], o_acc);
        }
        m_run = m_new;
    }

    // Write attention output in (b, n, h*d) layout (== transpose+reshape in ref)
    ob[((size_t)bi * SEQ_N + i) * DIM + hh * DH + lane] = o_acc / l_run;
}

// ---------------------------------------------------------------------------
// Launch: q = x@Wq+bq ; kv = x@Wkv+bkv ; p = pos@Wp+bp ; attn ; out = a@Wo+bo
// ---------------------------------------------------------------------------
extern "C" void kernel_launch(void* const* d_in, const int* in_sizes, int n_in,
                              void* d_out, int out_size, void* d_ws, size_t ws_size,
                              hipStream_t stream)
{
    const float* x    = (const float*)d_in[0];   // (2, 2048, 1024)
    const float* pos  = (const float*)d_in[1];   // (2048, 1024)
    const float* Wq   = (const float*)d_in[2];   // (1024, 1024)
    const float* bq   = (const float*)d_in[3];
    const float* Wkv  = (const float*)d_in[4];   // (1024, 2048)
    const float* bkv  = (const float*)d_in[5];
    const float* Wp   = (const float*)d_in[6];   // (1024, 64)
    const float* bp   = (const float*)d_in[7];
    const float* Wo   = (const float*)d_in[8];   // (1024, 1024)
    const float* bo   = (const float*)d_in[9];
    float* out = (float*)d_out;                  // (2, 2048, 1024)

    float* ws    = (float*)d_ws;
    float* qbuf  = ws;                                   // 4096*1024
    float* kvbuf = qbuf  + (size_t)4096 * 1024;          // 4096*2048
    float* pbuf  = kvbuf + (size_t)4096 * 2048;          // 2048*64
    float* abuf  = pbuf  + (size_t)2048 * 64;            // 4096*1024
    // total ws use: ~67.6 MB

    const int M = 2 * SEQ_N;   // 4096 rows (batch-major)

    dim3 blk(256);
    // q = x @ Wq + bq                (4096 x 1024 x 1024)
    gemm_bias_kernel<<<dim3(DIM / 64, M / 64), blk, 0, stream>>>(
        x, Wq, bq, qbuf, M, DIM, DIM);
    // kv = x @ Wkv + bkv             (4096 x 2048 x 1024)
    gemm_bias_kernel<<<dim3(2 * DIM / 64, M / 64), blk, 0, stream>>>(
        x, Wkv, bkv, kvbuf, M, 2 * DIM, DIM);
    // p = pos_emb @ Wp + bp          (2048 x 64 x 1024)
    gemm_bias_kernel<<<dim3(DH / 64, SEQ_N / 64), blk, 0, stream>>>(
        pos, Wp, bp, pbuf, SEQ_N, DH, DIM);
    // attention core (flash-style, causal + rel-pos bias)
    attn_kernel<<<dim3(SEQ_N / 4, 32), blk, 0, stream>>>(
        qbuf, kvbuf, pbuf, abuf);
    // out = abuf @ Wo + bo           (4096 x 1024 x 1024)
    gemm_bias_kernel<<<dim3(DIM / 64, M / 64), blk, 0, stream>>>(
        abuf, Wo, bo, out, M, DIM, DIM);
}

// Round 2
// 1936.208 us; speedup vs baseline: 1.7296x; 1.7296x over previous
//
#include <hip/hip_runtime.h>
#include <hip/hip_bf16.h>
#include <cstdint>
#include <cstddef>

#define SEQ_N 2048
#define DIM   1024
#define NHEAD 16
#define DH    64

// ---------------------------------------------------------------------------
// Generic fp32 GEMM: C[M,N] = A[M,K] @ B[K,N] + bias[N]
// 64x64 block tile, 16x16 threads, 4x4 per thread, BK=16.
// ---------------------------------------------------------------------------
__global__ __launch_bounds__(256) void gemm_bias_kernel(
    const float* __restrict__ A, const float* __restrict__ B,
    const float* __restrict__ bias, float* __restrict__ C,
    int M, int N, int K)
{
    __shared__ float As[16][68];
    __shared__ float Bs[16][68];

    const int tx = threadIdx.x & 15;
    const int ty = threadIdx.x >> 4;
    const int m0 = blockIdx.y * 64;
    const int n0 = blockIdx.x * 64;

    float acc[4][4] = {};

    for (int k0 = 0; k0 < K; k0 += 16) {
        #pragma unroll
        for (int t = 0; t < 4; ++t) {
            int idx = threadIdx.x + t * 256;
            int r = idx >> 4, c = idx & 15;
            As[c][r] = A[(size_t)(m0 + r) * K + k0 + c];
        }
        #pragma unroll
        for (int t = 0; t < 4; ++t) {
            int idx = threadIdx.x + t * 256;
            int r = idx >> 6, c = idx & 63;
            Bs[r][c] = B[(size_t)(k0 + r) * N + n0 + c];
        }
        __syncthreads();

        #pragma unroll
        for (int k = 0; k < 16; ++k) {
            float4 av = *(const float4*)&As[k][ty << 2];
            float4 bv = *(const float4*)&Bs[k][tx << 2];
            float a[4] = {av.x, av.y, av.z, av.w};
            float b[4] = {bv.x, bv.y, bv.z, bv.w};
            #pragma unroll
            for (int ii = 0; ii < 4; ++ii)
                #pragma unroll
                for (int jj = 0; jj < 4; ++jj)
                    acc[ii][jj] = fmaf(a[ii], b[jj], acc[ii][jj]);
        }
        __syncthreads();
    }

    float4 bb = *(const float4*)&bias[n0 + (tx << 2)];
    const float badd[4] = {bb.x, bb.y, bb.z, bb.w};
    #pragma unroll
    for (int ii = 0; ii < 4; ++ii) {
        int m = m0 + (ty << 2) + ii;
        float4 o;
        o.x = acc[ii][0] + badd[0];
        o.y = acc[ii][1] + badd[1];
        o.z = acc[ii][2] + badd[2];
        o.w = acc[ii][3] + badd[3];
        *(float4*)&C[(size_t)m * N + n0 + (tx << 2)] = o;
    }
}

// ---------------------------------------------------------------------------
// Flash attention, register-tiled: Br=64 x Bc=64 per block, 256 threads,
// 4x4 accumulators per thread (identical shape to the GEMM above).
//
// score[i,j] = scale * ( q_i . k_j + q_i . p[n-1-(i-j)] )   for j <= i
// Within a tile: bias column in the staged p-band = c0 + (jj-ii),
// c0 = 63 + 4*(tx-ty), so each thread needs band columns [c0-3, c0+3] --
// covered by two float4 reads at c0-3 and c0+1 (both 16B aligned).
// ---------------------------------------------------------------------------
__global__ __launch_bounds__(256) void attn_kernel(
    const float* __restrict__ qb,   // (b, n, DIM)
    const float* __restrict__ kvb,  // (b, n, 2*DIM)
    const float* __restrict__ pb,   // (n, DH)
    float* __restrict__ ob)         // (b, n, DIM)
{
    const int bh = blockIdx.y;
    const int bi = bh >> 4;
    const int hh = bh & 15;
    const int qblk = (int)gridDim.x - 1 - (int)blockIdx.x;  // big blocks first
    const int i0 = qblk << 6;
    const int tid = threadIdx.x;
    const int tx = tid & 15;
    const int ty = tid >> 4;

    __shared__ float Qs[64][68];    // [d][i_local]  (transposed)
    __shared__ float Ks[64][68];    // [d][j_local]  (transposed)
    __shared__ float Vs[64][68];    // [j_local][d]  (direct)
    __shared__ float Pb[64][132];   // [d][m_local]  p band, 128 cols used
    __shared__ float Ps2[64][68];   // [j_local][i_local] probabilities

    // Stage Q tile (transposed)
    #pragma unroll
    for (int t = 0; t < 4; ++t) {
        int idx = tid + (t << 8);
        int r = idx >> 4, f = (idx & 15) << 2;
        float4 v = *(const float4*)&qb[((size_t)bi * SEQ_N + i0 + r) * DIM + hh * DH + f];
        Qs[f + 0][r] = v.x; Qs[f + 1][r] = v.y; Qs[f + 2][r] = v.z; Qs[f + 3][r] = v.w;
    }

    float m_run[4] = {-1e30f, -1e30f, -1e30f, -1e30f};
    float l_run[4] = {};
    float O[4][4] = {};

    const int c0 = 63 + ((tx - ty) << 2);
    const int ntiles = qblk + 1;

    for (int jt = 0; jt < ntiles; ++jt) {
        const int j0 = jt << 6;
        __syncthreads();   // prior tile fully consumed (also covers Qs on jt=0)

        // Stage K (transposed) and V (direct)
        #pragma unroll
        for (int t = 0; t < 4; ++t) {
            int idx = tid + (t << 8);
            int r = idx >> 4, f = (idx & 15) << 2;
            const float* kvrow = kvb + ((size_t)bi * SEQ_N + j0 + r) * (2 * DIM) + hh * DH;
            float4 kv4 = *(const float4*)&kvrow[f];
            Ks[f + 0][r] = kv4.x; Ks[f + 1][r] = kv4.y;
            Ks[f + 2][r] = kv4.z; Ks[f + 3][r] = kv4.w;
            *(float4*)&Vs[r][f] = *(const float4*)&kvrow[DIM + f];
        }
        // Stage p band (transposed): rows m = base_m + r, r in [0,128)
        const int base_m = SEQ_N - 64 - i0 + j0;   // >= 0 always
        #pragma unroll
        for (int t = 0; t < 8; ++t) {
            int idx = tid + (t << 8);
            int r = idx >> 4, f = (idx & 15) << 2;
            int mr = base_m + r;
            if (mr > SEQ_N - 1) mr = SEQ_N - 1;    // rows past end are masked anyway
            float4 p4 = *(const float4*)&pb[(size_t)mr * DH + f];
            Pb[f + 0][r] = p4.x; Pb[f + 1][r] = p4.y;
            Pb[f + 2][r] = p4.z; Pb[f + 3][r] = p4.w;
        }
        __syncthreads();

        // S = Q K^T + bias   (4x4 per thread)
        float acc[4][4] = {};
        #pragma unroll 4
        for (int d = 0; d < 64; ++d) {
            float4 av = *(const float4*)&Qs[d][ty << 2];
            float4 bv = *(const float4*)&Ks[d][tx << 2];
            float4 p0 = *(const float4*)&Pb[d][c0 - 3];
            float4 p1 = *(const float4*)&Pb[d][c0 + 1];
            float a[4]  = {av.x, av.y, av.z, av.w};
            float b[4]  = {bv.x, bv.y, bv.z, bv.w};
            float pv[8] = {p0.x, p0.y, p0.z, p0.w, p1.x, p1.y, p1.z, p1.w};
            #pragma unroll
            for (int ii = 0; ii < 4; ++ii)
                #pragma unroll
                for (int jj = 0; jj < 4; ++jj) {
                    acc[ii][jj] = fmaf(a[ii], b[jj], acc[ii][jj]);
                    acc[ii][jj] = fmaf(a[ii], pv[jj - ii + 3], acc[ii][jj]);
                }
        }

        // scale + causal mask
        #pragma unroll
        for (int ii = 0; ii < 4; ++ii) {
            const int ig = i0 + (ty << 2) + ii;
            #pragma unroll
            for (int jj = 0; jj < 4; ++jj) {
                const int jg = j0 + (tx << 2) + jj;
                acc[ii][jj] = (jg <= ig) ? acc[ii][jj] * 0.125f : -1e30f;
            }
        }

        // online softmax (row groups = 16 consecutive lanes sharing ty)
        #pragma unroll
        for (int ii = 0; ii < 4; ++ii) {
            float rmax = fmaxf(fmaxf(acc[ii][0], acc[ii][1]),
                               fmaxf(acc[ii][2], acc[ii][3]));
            #pragma unroll
            for (int off = 1; off < 16; off <<= 1)
                rmax = fmaxf(rmax, __shfl_xor(rmax, off));
            const float mn = fmaxf(m_run[ii], rmax);

            float rsum = 0.0f;
            #pragma unroll
            for (int jj = 0; jj < 4; ++jj) {
                float e = __expf(acc[ii][jj] - mn);
                acc[ii][jj] = e;
                rsum += e;
            }
            #pragma unroll
            for (int off = 1; off < 16; off <<= 1)
                rsum += __shfl_xor(rsum, off);

            const float alpha = __expf(m_run[ii] - mn);
            l_run[ii] = l_run[ii] * alpha + rsum;
            m_run[ii] = mn;
            #pragma unroll
            for (int dd = 0; dd < 4; ++dd)
                O[ii][dd] *= alpha;
        }

        // P -> LDS (transposed [j][i])
        #pragma unroll
        for (int ii = 0; ii < 4; ++ii)
            #pragma unroll
            for (int jj = 0; jj < 4; ++jj)
                Ps2[(tx << 2) + jj][(ty << 2) + ii] = acc[ii][jj];
        __syncthreads();

        // O += P V
        #pragma unroll 4
        for (int j = 0; j < 64; ++j) {
            float4 pf = *(const float4*)&Ps2[j][ty << 2];
            float4 vf = *(const float4*)&Vs[j][tx << 2];
            float p[4] = {pf.x, pf.y, pf.z, pf.w};
            float v[4] = {vf.x, vf.y, vf.z, vf.w};
            #pragma unroll
            for (int ii = 0; ii < 4; ++ii)
                #pragma unroll
                for (int dd = 0; dd < 4; ++dd)
                    O[ii][dd] = fmaf(p[ii], v[dd], O[ii][dd]);
        }
    }

    // normalize + write (b, n, h*d)
    #pragma unroll
    for (int ii = 0; ii < 4; ++ii) {
        const float inv = 1.0f / l_run[ii];
        float4 o;
        o.x = O[ii][0] * inv; o.y = O[ii][1] * inv;
        o.z = O[ii][2] * inv; o.w = O[ii][3] * inv;
        ob[((size_t)bi * SEQ_N + i0 + (ty << 2) + ii) * DIM + hh * DH + (tx << 2)] = o.x,
        *(float4*)&ob[((size_t)bi * SEQ_N + i0 + (ty << 2) + ii) * DIM + hh * DH + (tx << 2)] = o;
    }
}

// ---------------------------------------------------------------------------
extern "C" void kernel_launch(void* const* d_in, const int* in_sizes, int n_in,
                              void* d_out, int out_size, void* d_ws, size_t ws_size,
                              hipStream_t stream)
{
    const float* x    = (const float*)d_in[0];
    const float* pos  = (const float*)d_in[1];
    const float* Wq   = (const float*)d_in[2];
    const float* bq   = (const float*)d_in[3];
    const float* Wkv  = (const float*)d_in[4];
    const float* bkv  = (const float*)d_in[5];
    const float* Wp   = (const float*)d_in[6];
    const float* bp   = (const float*)d_in[7];
    const float* Wo   = (const float*)d_in[8];
    const float* bo   = (const float*)d_in[9];
    float* out = (float*)d_out;

    float* ws    = (float*)d_ws;
    float* qbuf  = ws;
    float* kvbuf = qbuf  + (size_t)4096 * 1024;
    float* pbuf  = kvbuf + (size_t)4096 * 2048;
    float* abuf  = pbuf  + (size_t)2048 * 64;

    const int M = 2 * SEQ_N;

    dim3 blk(256);
    gemm_bias_kernel<<<dim3(DIM / 64, M / 64), blk, 0, stream>>>(
        x, Wq, bq, qbuf, M, DIM, DIM);
    gemm_bias_kernel<<<dim3(2 * DIM / 64, M / 64), blk, 0, stream>>>(
        x, Wkv, bkv, kvbuf, M, 2 * DIM, DIM);
    gemm_bias_kernel<<<dim3(DH / 64, SEQ_N / 64), blk, 0, stream>>>(
        pos, Wp, bp, pbuf, SEQ_N, DH, DIM);
    attn_kernel<<<dim3(SEQ_N / 64, 32), blk, 0, stream>>>(
        qbuf, kvbuf, pbuf, abuf);
    gemm_bias_kernel<<<dim3(DIM / 64, M / 64), blk, 0, stream>>>(
        abuf, Wo, bo, out, M, DIM, DIM);
}

// Round 3
// 443.244 us; speedup vs baseline: 7.5556x; 4.3683x over previous
//
#include <hip/hip_runtime.h>
#include <hip/hip_bf16.h>
#include <cstdint>
#include <cstddef>

#define SEQ_N 2048
#define DIM   1024
#define NHEAD 16
#define DH    64

typedef __bf16 bf16;
typedef __attribute__((ext_vector_type(8))) __bf16 bf16x8;
typedef __attribute__((ext_vector_type(4))) float f32x4;

// async global->LDS 16B copy: LDS dest = wave-uniform base + lane*16
__device__ __forceinline__ void gl_lds16(const bf16* g, bf16* l) {
    __builtin_amdgcn_global_load_lds(
        (const __attribute__((address_space(1))) unsigned int*)g,
        (__attribute__((address_space(3))) unsigned int*)l, 16, 0, 0);
}

// ---------------------------------------------------------------------------
// cast fp32 -> bf16 (contiguous)
// ---------------------------------------------------------------------------
__global__ __launch_bounds__(256) void cast_bf16_kernel(
    const float* __restrict__ in, bf16* __restrict__ out, int n)
{
    int i = (blockIdx.x * 256 + threadIdx.x) * 4;
    if (i < n) {
        float4 v = *(const float4*)&in[i];
        out[i + 0] = (bf16)v.x; out[i + 1] = (bf16)v.y;
        out[i + 2] = (bf16)v.z; out[i + 3] = (bf16)v.w;
    }
}

// ---------------------------------------------------------------------------
// transpose + cast: WT[n][k] = (bf16) W[k][n]
// ---------------------------------------------------------------------------
__global__ __launch_bounds__(256) void transpose_cast_kernel(
    const float* __restrict__ W, bf16* __restrict__ WT, int K, int N)
{
    __shared__ float t[32][33];
    int k0 = blockIdx.y * 32, n0 = blockIdx.x * 32;
    int tx = threadIdx.x & 31, ty = threadIdx.x >> 5;
    #pragma unroll
    for (int r = ty; r < 32; r += 8)
        t[r][tx] = W[(size_t)(k0 + r) * N + n0 + tx];
    __syncthreads();
    #pragma unroll
    for (int r = ty; r < 32; r += 8)
        WT[(size_t)(n0 + r) * K + k0 + tx] = (bf16)t[tx][r];
}

// ---------------------------------------------------------------------------
// bf16 MFMA GEMM, m97 structure: C[M,N] = A[M,K] @ BT[N,K]^T + bias
// 128x128 tile, BK=64, 4 waves (2x2), each wave 64x64 = 4x4 of 16x16x32.
// LDS tiles XOR-chunk-swizzled: phys_chunk = log_chunk ^ (row&7) -> 2-way free.
// MODE 0: bf16 out; MODE 1: fp32 out; MODE 2: kv split (K natural, V transposed).
// ---------------------------------------------------------------------------
template<int MODE>
__global__ __launch_bounds__(256) void mfma_gemm_bt(
    const bf16* __restrict__ A, const bf16* __restrict__ BT,
    const float* __restrict__ bias, void* __restrict__ C,
    bf16* __restrict__ Vt, int M, int N, int K)
{
    __shared__ bf16 At[128 * 64];
    __shared__ bf16 Bt[128 * 64];
    const int tid = threadIdx.x;
    const int w = tid >> 6, lane = tid & 63;
    const int wm = w >> 1, wn = w & 1;
    const int m0 = blockIdx.y * 128, n0 = blockIdx.x * 128;
    const int lr = lane >> 3, lc = lane & 7;
    const int c_log = lc ^ lr;           // logical chunk fetched by this lane
    const int q = lane >> 4, ln15 = lane & 15;

    f32x4 acc[4][4] = {};

    for (int k0 = 0; k0 < K; k0 += 64) {
        __syncthreads();
        #pragma unroll
        for (int t = 0; t < 4; ++t) {
            int r = 32 * w + 8 * t + lr;
            gl_lds16(&A[(size_t)(m0 + r) * K + k0 + c_log * 8],
                     &At[(32 * w + 8 * t) * 64]);
            gl_lds16(&BT[(size_t)(n0 + r) * K + k0 + c_log * 8],
                     &Bt[(32 * w + 8 * t) * 64]);
        }
        __syncthreads();

        bf16x8 af[2][4], bfr[2][4];
        #pragma unroll
        for (int ks = 0; ks < 2; ++ks)
            #pragma unroll
            for (int s = 0; s < 4; ++s) {
                int ra = 64 * wm + 16 * s + ln15;
                af[ks][s]  = *(const bf16x8*)&At[(ra * 8 + ((4 * ks + q) ^ (ra & 7))) * 8];
                int rb = 64 * wn + 16 * s + ln15;
                bfr[ks][s] = *(const bf16x8*)&Bt[(rb * 8 + ((4 * ks + q) ^ (rb & 7))) * 8];
            }
        #pragma unroll
        for (int ks = 0; ks < 2; ++ks)
            #pragma unroll
            for (int si = 0; si < 4; ++si)
                #pragma unroll
                for (int sj = 0; sj < 4; ++sj)
                    acc[si][sj] = __builtin_amdgcn_mfma_f32_16x16x32_bf16(
                        af[ks][si], bfr[ks][sj], acc[si][sj], 0, 0, 0);
    }

    // epilogue: C/D layout col=lane&15, row=quad*4+reg
    #pragma unroll
    for (int si = 0; si < 4; ++si)
        #pragma unroll
        for (int sj = 0; sj < 4; ++sj)
            #pragma unroll
            for (int r = 0; r < 4; ++r) {
                int row = m0 + 64 * wm + 16 * si + 4 * q + r;
                int col = n0 + 64 * wn + 16 * sj + ln15;
                float v = acc[si][sj][r] + bias[col];
                if (MODE == 0) {
                    ((bf16*)C)[(size_t)row * N + col] = (bf16)v;
                } else if (MODE == 1) {
                    ((float*)C)[(size_t)row * N + col] = v;
                } else {
                    if (col < DIM) {
                        ((bf16*)C)[(size_t)row * DIM + col] = (bf16)v;
                    } else {
                        int c2 = col - DIM, h = c2 >> 6, d = c2 & 63;
                        int b = row >> 11, t = row & (SEQ_N - 1);
                        Vt[((size_t)((b * NHEAD + h) * DH + d)) * SEQ_N + t] = (bf16)v;
                    }
                }
            }
}

// ---------------------------------------------------------------------------
// small fp32 GEMM -> bf16 out (for p = pos_emb @ Wp + bp, N=64)
// ---------------------------------------------------------------------------
__global__ __launch_bounds__(256) void gemm_bias_p_kernel(
    const float* __restrict__ A, const float* __restrict__ B,
    const float* __restrict__ bias, bf16* __restrict__ C,
    int M, int N, int K)
{
    __shared__ float As[16][68];
    __shared__ float Bs[16][68];
    const int tx = threadIdx.x & 15, ty = threadIdx.x >> 4;
    const int m0 = blockIdx.y * 64, n0 = blockIdx.x * 64;
    float acc[4][4] = {};

    for (int k0 = 0; k0 < K; k0 += 16) {
        #pragma unroll
        for (int t = 0; t < 4; ++t) {
            int idx = threadIdx.x + t * 256;
            int r = idx >> 4, c = idx & 15;
            As[c][r] = A[(size_t)(m0 + r) * K + k0 + c];
        }
        #pragma unroll
        for (int t = 0; t < 4; ++t) {
            int idx = threadIdx.x + t * 256;
            int r = idx >> 6, c = idx & 63;
            Bs[r][c] = B[(size_t)(k0 + r) * N + n0 + c];
        }
        __syncthreads();
        #pragma unroll
        for (int k = 0; k < 16; ++k) {
            float4 av = *(const float4*)&As[k][ty << 2];
            float4 bv = *(const float4*)&Bs[k][tx << 2];
            float a[4] = {av.x, av.y, av.z, av.w};
            float b[4] = {bv.x, bv.y, bv.z, bv.w};
            #pragma unroll
            for (int ii = 0; ii < 4; ++ii)
                #pragma unroll
                for (int jj = 0; jj < 4; ++jj)
                    acc[ii][jj] = fmaf(a[ii], b[jj], acc[ii][jj]);
        }
        __syncthreads();
    }
    float4 bb = *(const float4*)&bias[n0 + (tx << 2)];
    const float badd[4] = {bb.x, bb.y, bb.z, bb.w};
    #pragma unroll
    for (int ii = 0; ii < 4; ++ii) {
        int m = m0 + (ty << 2) + ii;
        #pragma unroll
        for (int jj = 0; jj < 4; ++jj)
            C[(size_t)m * N + n0 + (tx << 2) + jj] = (bf16)(acc[ii][jj] + badd[jj]);
    }
}

// ---------------------------------------------------------------------------
// MFMA flash attention with rel-shift bias.
// Block: 64 q-rows (4 waves x 16-row strips) x 64-key tiles.
// score[i,j] = 0.125*(q_i.k_j + q_i.p[n-1-(i-j)]), j<=i.
// Bias via S2 = Q @ Pband^T (wave w needs band cols [48-16w,128-16w) = 5
// subtiles); gather col_local = 15 - il + jl. P->A-frag via LDS Pt[j][i].
// ---------------------------------------------------------------------------
__global__ __launch_bounds__(256) void attn_mfma_kernel(
    const bf16* __restrict__ qb,   // [4096][1024]
    const bf16* __restrict__ kb,   // [4096][1024]
    const bf16* __restrict__ vt,   // [(b,h,d)][2048]
    const bf16* __restrict__ pbuf, // [2048][64]
    bf16* __restrict__ ob)         // [4096][1024]
{
    const int bh = blockIdx.y, bi = bh >> 4, hh = bh & 15;
    const int qblk = (int)gridDim.x - 1 - (int)blockIdx.x;  // big blocks first
    const int i0 = qblk * 64;
    const int tid = threadIdx.x, w = tid >> 6, lane = tid & 63;
    const int q = lane >> 4, ln15 = lane & 15;
    const int lr = lane >> 3, lc = lane & 7, c_log = lc ^ lr;

    __shared__ bf16  Qs[64 * 64];
    __shared__ bf16  Ks[64 * 64];
    __shared__ bf16  Vs[64 * 64];        // [d][j]
    __shared__ bf16  Pb[2][64 * 64];     // band rows 0..127
    __shared__ float Pt[4][64][17];      // per-wave P^T [j][i], 2-way banks
    __shared__ bf16  S2s[4][16][88];     // per-wave bias, col_local = 15-il+jl

    // stage Q once (wave w rows 16w..16w+16)
    const bf16* qbase = qb + ((size_t)(bi * SEQ_N + i0)) * DIM + hh * DH;
    #pragma unroll
    for (int t = 0; t < 2; ++t) {
        int r = 16 * w + 8 * t + lr;
        gl_lds16(qbase + (size_t)r * DIM + c_log * 8, &Qs[(16 * w + 8 * t) * 64]);
    }
    __syncthreads();
    bf16x8 qf[2];
    {
        int rq = 16 * w + ln15;
        qf[0] = *(const bf16x8*)&Qs[(rq * 8 + ((q    ) ^ (rq & 7))) * 8];
        qf[1] = *(const bf16x8*)&Qs[(rq * 8 + ((4 + q) ^ (rq & 7))) * 8];
    }

    float m_run[4] = {-1e30f, -1e30f, -1e30f, -1e30f};
    float l_run[4] = {0.f, 0.f, 0.f, 0.f};
    f32x4 O[4] = {};

    const bf16* kbase = kb + ((size_t)bi * SEQ_N) * DIM + hh * DH;
    const bf16* vbase = vt + ((size_t)(bi * NHEAD + hh) * DH) * SEQ_N;

    for (int jt = 0; jt <= qblk; ++jt) {
        const int j0 = jt * 64;
        __syncthreads();   // previous tile consumed
        #pragma unroll
        for (int t = 0; t < 2; ++t) {
            int r = 16 * w + 8 * t + lr;
            gl_lds16(kbase + (size_t)(j0 + r) * DIM + c_log * 8, &Ks[(16 * w + 8 * t) * 64]);
            gl_lds16(vbase + (size_t)r * SEQ_N + j0 + c_log * 8, &Vs[(16 * w + 8 * t) * 64]);
        }
        const int base_m = SEQ_N - 64 - i0 + j0;   // >= 0
        #pragma unroll
        for (int half = 0; half < 2; ++half)
            #pragma unroll
            for (int t = 0; t < 2; ++t) {
                int r = 16 * w + 8 * t + lr;
                int m = base_m + half * 64 + r;
                if (m > SEQ_N - 1) m = SEQ_N - 1;   // masked rows anyway
                gl_lds16(pbuf + (size_t)m * DH + c_log * 8, &Pb[half][(16 * w + 8 * t) * 64]);
            }
        __syncthreads();

        // ---- S2 = Q . Pband^T (5 subtiles for this wave) ----
        #pragma unroll
        for (int sbl = 0; sbl < 5; ++sbl) {
            int sb = sbl + 3 - w;              // absolute band subtile
            f32x4 s2 = {};
            #pragma unroll
            for (int ks = 0; ks < 2; ++ks) {
                int br = sb * 16 + ln15;
                int rr = br & 63;
                bf16x8 bfrag = *(const bf16x8*)&Pb[br >> 6][(rr * 8 + ((4 * ks + q) ^ (rr & 7))) * 8];
                s2 = __builtin_amdgcn_mfma_f32_16x16x32_bf16(qf[ks], bfrag, s2, 0, 0, 0);
            }
            #pragma unroll
            for (int r = 0; r < 4; ++r)
                S2s[w][4 * q + r][16 * sbl + ln15] = (bf16)s2[r];
        }

        // ---- S1 = Q.K^T + bias, scale, mask ----
        float sv[4][4];
        #pragma unroll
        for (int sn = 0; sn < 4; ++sn) {
            f32x4 s1 = {};
            #pragma unroll
            for (int ks = 0; ks < 2; ++ks) {
                int rk = sn * 16 + ln15;
                bf16x8 kfrag = *(const bf16x8*)&Ks[(rk * 8 + ((4 * ks + q) ^ (rk & 7))) * 8];
                s1 = __builtin_amdgcn_mfma_f32_16x16x32_bf16(qf[ks], kfrag, s1, 0, 0, 0);
            }
            #pragma unroll
            for (int r = 0; r < 4; ++r) {
                int il = 4 * q + r, jl = 16 * sn + ln15;
                float bias = (float)S2s[w][il][15 - il + jl];
                float val = (s1[r] + bias) * 0.125f;
                sv[sn][r] = ((j0 + jl) <= (i0 + 16 * w + il)) ? val : -1e30f;
            }
        }

        // ---- online softmax (rows spread over 16 lanes of each quad) ----
        float alpha[4], pexp[4][4];
        #pragma unroll
        for (int r = 0; r < 4; ++r) {
            float rmax = fmaxf(fmaxf(sv[0][r], sv[1][r]), fmaxf(sv[2][r], sv[3][r]));
            #pragma unroll
            for (int off = 1; off < 16; off <<= 1)
                rmax = fmaxf(rmax, __shfl_xor(rmax, off));
            float mn = fmaxf(m_run[r], rmax);
            float rsum = 0.f;
            #pragma unroll
            for (int sn = 0; sn < 4; ++sn) {
                float e = __expf(sv[sn][r] - mn);
                pexp[sn][r] = e; rsum += e;
            }
            #pragma unroll
            for (int off = 1; off < 16; off <<= 1)
                rsum += __shfl_xor(rsum, off);
            alpha[r] = __expf(m_run[r] - mn);
            l_run[r] = l_run[r] * alpha[r] + rsum;
            m_run[r] = mn;
        }
        #pragma unroll
        for (int sn = 0; sn < 4; ++sn)
            #pragma unroll
            for (int r = 0; r < 4; ++r)
                Pt[w][16 * sn + ln15][4 * q + r] = pexp[sn][r];
        #pragma unroll
        for (int sd = 0; sd < 4; ++sd)
            #pragma unroll
            for (int r = 0; r < 4; ++r)
                O[sd][r] *= alpha[r];

        // ---- O += P @ V ----
        #pragma unroll
        for (int ks = 0; ks < 2; ++ks) {
            bf16x8 pf;
            #pragma unroll
            for (int jj = 0; jj < 8; ++jj)
                pf[jj] = (bf16)Pt[w][32 * ks + 8 * q + jj][ln15];
            #pragma unroll
            for (int sd = 0; sd < 4; ++sd) {
                int rv = sd * 16 + ln15;   // Vs row = d
                bf16x8 vfrag = *(const bf16x8*)&Vs[(rv * 8 + ((4 * ks + q) ^ (rv & 7))) * 8];
                O[sd] = __builtin_amdgcn_mfma_f32_16x16x32_bf16(pf, vfrag, O[sd], 0, 0, 0);
            }
        }
    }

    #pragma unroll
    for (int sd = 0; sd < 4; ++sd)
        #pragma unroll
        for (int r = 0; r < 4; ++r) {
            int row = bi * SEQ_N + i0 + 16 * w + 4 * q + r;
            ob[(size_t)row * DIM + hh * DH + 16 * sd + ln15] = (bf16)(O[sd][r] / l_run[r]);
        }
}

// ---------------------------------------------------------------------------
extern "C" void kernel_launch(void* const* d_in, const int* in_sizes, int n_in,
                              void* d_out, int out_size, void* d_ws, size_t ws_size,
                              hipStream_t stream)
{
    const float* x    = (const float*)d_in[0];
    const float* pos  = (const float*)d_in[1];
    const float* Wq   = (const float*)d_in[2];
    const float* bq   = (const float*)d_in[3];
    const float* Wkv  = (const float*)d_in[4];
    const float* bkv  = (const float*)d_in[5];
    const float* Wp   = (const float*)d_in[6];
    const float* bp   = (const float*)d_in[7];
    const float* Wo   = (const float*)d_in[8];
    const float* bo   = (const float*)d_in[9];
    float* out = (float*)d_out;

    const int M = 2 * SEQ_N;   // 4096
    char* ws = (char*)d_ws;
    bf16* xb    = (bf16*)ws;                       ws += (size_t)M * DIM * 2;        // 8MB
    bf16* WqT   = (bf16*)ws;                       ws += (size_t)DIM * DIM * 2;      // 2MB
    bf16* WkvT  = (bf16*)ws;                       ws += (size_t)2 * DIM * DIM * 2;  // 4MB
    bf16* WoT   = (bf16*)ws;                       ws += (size_t)DIM * DIM * 2;      // 2MB
    bf16* qbuf  = (bf16*)ws;                       ws += (size_t)M * DIM * 2;        // 8MB
    bf16* kbuf  = (bf16*)ws;                       ws += (size_t)M * DIM * 2;        // 8MB
    bf16* vtbuf = (bf16*)ws;                       ws += (size_t)M * DIM * 2;        // 8MB
    bf16* pbuf  = (bf16*)ws;                       ws += (size_t)SEQ_N * DH * 2;     // 256KB
    bf16* abuf  = (bf16*)ws;                                                        // 8MB

    dim3 blk(256);
    // casts / transposes
    cast_bf16_kernel<<<dim3(M * DIM / 1024), blk, 0, stream>>>(x, xb, M * DIM);
    transpose_cast_kernel<<<dim3(DIM / 32, DIM / 32), blk, 0, stream>>>(Wq, WqT, DIM, DIM);
    transpose_cast_kernel<<<dim3(2 * DIM / 32, DIM / 32), blk, 0, stream>>>(Wkv, WkvT, DIM, 2 * DIM);
    transpose_cast_kernel<<<dim3(DIM / 32, DIM / 32), blk, 0, stream>>>(Wo, WoT, DIM, DIM);

    // projections (bf16 MFMA)
    mfma_gemm_bt<0><<<dim3(DIM / 128, M / 128), blk, 0, stream>>>(
        xb, WqT, bq, (void*)qbuf, nullptr, M, DIM, DIM);
    mfma_gemm_bt<2><<<dim3(2 * DIM / 128, M / 128), blk, 0, stream>>>(
        xb, WkvT, bkv, (void*)kbuf, vtbuf, M, 2 * DIM, DIM);
    gemm_bias_p_kernel<<<dim3(1, SEQ_N / 64), blk, 0, stream>>>(
        pos, Wp, bp, pbuf, SEQ_N, DH, DIM);

    // attention core
    attn_mfma_kernel<<<dim3(SEQ_N / 64, 32), blk, 0, stream>>>(
        qbuf, kbuf, vtbuf, pbuf, abuf);

    // output projection (fp32 out)
    mfma_gemm_bt<1><<<dim3(DIM / 128, M / 128), blk, 0, stream>>>(
        abuf, WoT, bo, (void*)out, nullptr, M, DIM, DIM);
}

// Round 4
// 351.820 us; speedup vs baseline: 9.5189x; 1.2599x over previous
//
#include <hip/hip_runtime.h>
#include <hip/hip_bf16.h>
#include <cstdint>
#include <cstddef>

#define SEQ_N 2048
#define DIM   1024
#define NHEAD 16
#define DH    64

typedef __bf16 bf16;
typedef __attribute__((ext_vector_type(8))) __bf16 bf16x8;
typedef __attribute__((ext_vector_type(4))) float f32x4;

// async global->LDS 16B copy: LDS dest = wave-uniform base + lane*16
__device__ __forceinline__ void gl_lds16(const bf16* g, bf16* l) {
    __builtin_amdgcn_global_load_lds(
        (const __attribute__((address_space(1))) unsigned int*)g,
        (__attribute__((address_space(3))) unsigned int*)l, 16, 0, 0);
}

// ---------------------------------------------------------------------------
// cast fp32 -> bf16 (contiguous)
// ---------------------------------------------------------------------------
__global__ __launch_bounds__(256) void cast_bf16_kernel(
    const float* __restrict__ in, bf16* __restrict__ out, int n)
{
    int i = (blockIdx.x * 256 + threadIdx.x) * 4;
    if (i < n) {
        float4 v = *(const float4*)&in[i];
        out[i + 0] = (bf16)v.x; out[i + 1] = (bf16)v.y;
        out[i + 2] = (bf16)v.z; out[i + 3] = (bf16)v.w;
    }
}

// ---------------------------------------------------------------------------
// transpose + cast: WT[n][k] = (bf16) W[k][n]
// ---------------------------------------------------------------------------
__global__ __launch_bounds__(256) void transpose_cast_kernel(
    const float* __restrict__ W, bf16* __restrict__ WT, int K, int N)
{
    __shared__ float t[32][33];
    int k0 = blockIdx.y * 32, n0 = blockIdx.x * 32;
    int tx = threadIdx.x & 31, ty = threadIdx.x >> 5;
    #pragma unroll
    for (int r = ty; r < 32; r += 8)
        t[r][tx] = W[(size_t)(k0 + r) * N + n0 + tx];
    __syncthreads();
    #pragma unroll
    for (int r = ty; r < 32; r += 8)
        WT[(size_t)(n0 + r) * K + k0 + tx] = (bf16)t[tx][r];
}

// ---------------------------------------------------------------------------
// bf16 MFMA GEMM (m97 structure): C[M,N] = A[M,K] @ BT[N,K]^T + bias
// MODE 0: bf16 out; MODE 1: fp32 out; MODE 2: kv split (K natural, V transp.)
// ---------------------------------------------------------------------------
template<int MODE>
__global__ __launch_bounds__(256) void mfma_gemm_bt(
    const bf16* __restrict__ A, const bf16* __restrict__ BT,
    const float* __restrict__ bias, void* __restrict__ C,
    bf16* __restrict__ Vt, int M, int N, int K)
{
    __shared__ bf16 At[128 * 64];
    __shared__ bf16 Bt[128 * 64];
    const int tid = threadIdx.x;
    const int w = tid >> 6, lane = tid & 63;
    const int wm = w >> 1, wn = w & 1;
    const int m0 = blockIdx.y * 128, n0 = blockIdx.x * 128;
    const int lr = lane >> 3, lc = lane & 7;
    const int c_log = lc ^ lr;
    const int q = lane >> 4, ln15 = lane & 15;

    f32x4 acc[4][4] = {};

    for (int k0 = 0; k0 < K; k0 += 64) {
        __syncthreads();
        #pragma unroll
        for (int t = 0; t < 4; ++t) {
            int r = 32 * w + 8 * t + lr;
            gl_lds16(&A[(size_t)(m0 + r) * K + k0 + c_log * 8],
                     &At[(32 * w + 8 * t) * 64]);
            gl_lds16(&BT[(size_t)(n0 + r) * K + k0 + c_log * 8],
                     &Bt[(32 * w + 8 * t) * 64]);
        }
        __syncthreads();

        bf16x8 af[2][4], bfr[2][4];
        #pragma unroll
        for (int ks = 0; ks < 2; ++ks)
            #pragma unroll
            for (int s = 0; s < 4; ++s) {
                int ra = 64 * wm + 16 * s + ln15;
                af[ks][s]  = *(const bf16x8*)&At[(ra * 8 + ((4 * ks + q) ^ (ra & 7))) * 8];
                int rb = 64 * wn + 16 * s + ln15;
                bfr[ks][s] = *(const bf16x8*)&Bt[(rb * 8 + ((4 * ks + q) ^ (rb & 7))) * 8];
            }
        #pragma unroll
        for (int ks = 0; ks < 2; ++ks)
            #pragma unroll
            for (int si = 0; si < 4; ++si)
                #pragma unroll
                for (int sj = 0; sj < 4; ++sj)
                    acc[si][sj] = __builtin_amdgcn_mfma_f32_16x16x32_bf16(
                        af[ks][si], bfr[ks][sj], acc[si][sj], 0, 0, 0);
    }

    #pragma unroll
    for (int si = 0; si < 4; ++si)
        #pragma unroll
        for (int sj = 0; sj < 4; ++sj)
            #pragma unroll
            for (int r = 0; r < 4; ++r) {
                int row = m0 + 64 * wm + 16 * si + 4 * q + r;
                int col = n0 + 64 * wn + 16 * sj + ln15;
                float v = acc[si][sj][r] + bias[col];
                if (MODE == 0) {
                    ((bf16*)C)[(size_t)row * N + col] = (bf16)v;
                } else if (MODE == 1) {
                    ((float*)C)[(size_t)row * N + col] = v;
                } else {
                    if (col < DIM) {
                        ((bf16*)C)[(size_t)row * DIM + col] = (bf16)v;
                    } else {
                        int c2 = col - DIM, h = c2 >> 6, d = c2 & 63;
                        int b = row >> 11, t = row & (SEQ_N - 1);
                        Vt[((size_t)((b * NHEAD + h) * DH + d)) * SEQ_N + t] = (bf16)v;
                    }
                }
            }
}

// ---------------------------------------------------------------------------
// p = pos_emb @ Wp + bp, written in MFMA-B-fragment-ready layout:
// pfrag[(((sb*2 + ks)*64 + qd*16 + lnp)*8 + e]  where p-row = 16*sb + lnp,
// d = 32*ks + 8*qd + e.  A wave's B-frag load for subtile sb is then a
// contiguous, fully coalesced 1KB read (lane -> +16B).
// ---------------------------------------------------------------------------
__global__ __launch_bounds__(256) void gemm_bias_p_kernel(
    const float* __restrict__ A, const float* __restrict__ B,
    const float* __restrict__ bias, bf16* __restrict__ pfrag,
    int M, int N, int K)
{
    __shared__ float As[16][68];
    __shared__ float Bs[16][68];
    const int tx = threadIdx.x & 15, ty = threadIdx.x >> 4;
    const int m0 = blockIdx.y * 64;
    float acc[4][4] = {};

    for (int k0 = 0; k0 < K; k0 += 16) {
        #pragma unroll
        for (int t = 0; t < 4; ++t) {
            int idx = threadIdx.x + t * 256;
            int r = idx >> 4, c = idx & 15;
            As[c][r] = A[(size_t)(m0 + r) * K + k0 + c];
        }
        #pragma unroll
        for (int t = 0; t < 4; ++t) {
            int idx = threadIdx.x + t * 256;
            int r = idx >> 6, c = idx & 63;
            Bs[r][c] = B[(size_t)(k0 + r) * N + c];
        }
        __syncthreads();
        #pragma unroll
        for (int k = 0; k < 16; ++k) {
            float4 av = *(const float4*)&As[k][ty << 2];
            float4 bv = *(const float4*)&Bs[k][tx << 2];
            float a[4] = {av.x, av.y, av.z, av.w};
            float b[4] = {bv.x, bv.y, bv.z, bv.w};
            #pragma unroll
            for (int ii = 0; ii < 4; ++ii)
                #pragma unroll
                for (int jj = 0; jj < 4; ++jj)
                    acc[ii][jj] = fmaf(a[ii], b[jj], acc[ii][jj]);
        }
        __syncthreads();
    }
    #pragma unroll
    for (int ii = 0; ii < 4; ++ii) {
        int row = m0 + (ty << 2) + ii;
        int sb = row >> 4, lnp = row & 15;
        #pragma unroll
        for (int jj = 0; jj < 4; ++jj) {
            int d = (tx << 2) + jj;
            int ks = d >> 5, qd = (d >> 3) & 3, e = d & 7;
            pfrag[(((size_t)sb * 2 + ks) * 64 + qd * 16 + lnp) * 8 + e] =
                (bf16)(acc[ii][jj] + bias[d]);
        }
    }
}

// ---------------------------------------------------------------------------
// MFMA flash attention, O^T formulation + register S2 ring.
// Block = 4 waves; wave w owns 16 q-rows of a 64-row q-tile. Each block
// processes q-tiles {bx, 31-bx} sequentially -> uniform 33 iters/block.
//
// score[i,j] = 0.125*(q_i.k_j + q_i.p[2047-(i-j)]), j<=i.
// Band window per wave = 5 aligned 16-row p-subtiles starting at abs subtile
// A0+4*jt, A0 = 127-4*qblk-w; shifts +4/iter (overlap 1) -> keep 5 S2
// accumulators in registers, recompute 4/iter; gather bias by intra-quad
// lane rotation (sft = 15-il+ln15).
// PV as O^T = V^T (A-frag, = Vs reads) @ P^T (B-frag from natural-layout
// bf16 P store) -> no P transpose round-trip; alpha/l redistributed to
// lane=i by 4 shuffles.
// ---------------------------------------------------------------------------
__global__ __launch_bounds__(256) void attn_mfma_kernel(
    const bf16* __restrict__ qb,    // [4096][1024]
    const bf16* __restrict__ kb,    // [4096][1024]
    const bf16* __restrict__ vt,    // [(b,h,d)][2048]
    const bf16* __restrict__ pfrag, // fragment-ready p (256KB)
    bf16* __restrict__ ob)          // [4096][1024]
{
    const int bh = blockIdx.y, bi = bh >> 4, hh = bh & 15;
    const int bx = blockIdx.x;                 // 0..15
    const int tid = threadIdx.x, w = tid >> 6, lane = tid & 63;
    const int q = lane >> 4, ln15 = lane & 15;
    const int lr = lane >> 3, c_log = (lane & 7) ^ lr;

    __shared__ __align__(16) bf16 Qs[64 * 64];
    __shared__ __align__(16) bf16 Ks[64 * 64];
    __shared__ __align__(16) bf16 Vs[64 * 64];   // [d][j]
    __shared__ __align__(16) bf16 Pst[4][16][72]; // per-wave P[i][j], bf16

    const bf16* kbase = kb + ((size_t)bi * SEQ_N) * DIM + hh * DH;
    const bf16* vbase = vt + ((size_t)(bi * NHEAD + hh) * DH) * SEQ_N;

    for (int ph = 0; ph < 2; ++ph) {
        const int qblk = ph ? (31 - bx) : bx;
        const int i0 = qblk << 6;

        __syncthreads();   // protect LDS from previous phase readers
        const bf16* qbase = qb + ((size_t)(bi * SEQ_N + i0)) * DIM + hh * DH;
        #pragma unroll
        for (int t = 0; t < 2; ++t)
            gl_lds16(qbase + (size_t)(16 * w + 8 * t + lr) * DIM + c_log * 8,
                     &Qs[(16 * w + 8 * t) * 64]);
        __syncthreads();

        bf16x8 qf0, qf1;
        {
            int rq = 16 * w + ln15;
            qf0 = *(const bf16x8*)&Qs[(rq * 8 + ((q    ) ^ (rq & 7))) * 8];
            qf1 = *(const bf16x8*)&Qs[(rq * 8 + ((4 + q) ^ (rq & 7))) * 8];
        }

        const int A0 = 127 - 4 * qblk - w;
        f32x4 s2r[5];
        {
            bf16x8 f0 = *(const bf16x8*)&pfrag[(((size_t)A0 * 2 + 0) * 64 + lane) * 8];
            bf16x8 f1 = *(const bf16x8*)&pfrag[(((size_t)A0 * 2 + 1) * 64 + lane) * 8];
            f32x4 a = {0.f, 0.f, 0.f, 0.f};
            a = __builtin_amdgcn_mfma_f32_16x16x32_bf16(qf0, f0, a, 0, 0, 0);
            a = __builtin_amdgcn_mfma_f32_16x16x32_bf16(qf1, f1, a, 0, 0, 0);
            s2r[4] = a;
        }

        float m_run[4] = {-1e30f, -1e30f, -1e30f, -1e30f};
        float l_run[4] = {0.f, 0.f, 0.f, 0.f};
        f32x4 O_T[4] = {};

        for (int jt = 0; jt <= qblk; ++jt) {
            const int j0 = jt << 6;
            __syncthreads();
            #pragma unroll
            for (int t = 0; t < 2; ++t) {
                int r = 16 * w + 8 * t + lr;
                gl_lds16(kbase + (size_t)(j0 + r) * DIM + c_log * 8,
                         &Ks[(16 * w + 8 * t) * 64]);
                gl_lds16(vbase + (size_t)r * SEQ_N + j0 + c_log * 8,
                         &Vs[(16 * w + 8 * t) * 64]);
            }
            // band fragment loads (coalesced 1KB each, L2-hot)
            bf16x8 bf_[4][2];
            #pragma unroll
            for (int s = 1; s <= 4; ++s) {
                int sb = A0 + 4 * jt + s;
                if (sb > 127) sb = 127;              // masked region anyway
                bf_[s - 1][0] = *(const bf16x8*)&pfrag[(((size_t)sb * 2 + 0) * 64 + lane) * 8];
                bf_[s - 1][1] = *(const bf16x8*)&pfrag[(((size_t)sb * 2 + 1) * 64 + lane) * 8];
            }
            __syncthreads();

            // ---- S2 ring update ----
            s2r[0] = s2r[4];
            #pragma unroll
            for (int s = 1; s <= 4; ++s) {
                f32x4 a = {0.f, 0.f, 0.f, 0.f};
                a = __builtin_amdgcn_mfma_f32_16x16x32_bf16(qf0, bf_[s - 1][0], a, 0, 0, 0);
                a = __builtin_amdgcn_mfma_f32_16x16x32_bf16(qf1, bf_[s - 1][1], a, 0, 0, 0);
                s2r[s] = a;
            }

            // ---- S1 = Q.K^T ----
            f32x4 s1[4];
            #pragma unroll
            for (int sn = 0; sn < 4; ++sn) {
                int rk = 16 * sn + ln15;
                bf16x8 k0 = *(const bf16x8*)&Ks[(rk * 8 + ((q    ) ^ (rk & 7))) * 8];
                bf16x8 k1 = *(const bf16x8*)&Ks[(rk * 8 + ((4 + q) ^ (rk & 7))) * 8];
                f32x4 a = {0.f, 0.f, 0.f, 0.f};
                a = __builtin_amdgcn_mfma_f32_16x16x32_bf16(qf0, k0, a, 0, 0, 0);
                a = __builtin_amdgcn_mfma_f32_16x16x32_bf16(qf1, k1, a, 0, 0, 0);
                s1[sn] = a;
            }

            // ---- gather bias from s2r via intra-quad rotation; scale+mask ----
            float sv[4][4];   // [sn][r]
            #pragma unroll
            for (int r = 0; r < 4; ++r) {
                int il = 4 * q + r;
                int sft = 15 - il + ln15;            // 0..30
                int srcl = (q << 4) | (sft & 15);
                float sh[5];
                #pragma unroll
                for (int s = 0; s < 5; ++s)
                    sh[s] = __shfl(s2r[s][r], srcl);
                bool hi = sft >= 16;
                int ig = i0 + 16 * w + il;
                #pragma unroll
                for (int sn = 0; sn < 4; ++sn) {
                    float b = hi ? sh[sn + 1] : sh[sn];
                    int jg = j0 + 16 * sn + ln15;
                    sv[sn][r] = (jg <= ig) ? (s1[sn][r] + b) * 0.125f : -1e30f;
                }
            }

            // ---- online softmax per row r (16-lane row groups) ----
            float alpha[4];
            #pragma unroll
            for (int r = 0; r < 4; ++r) {
                float rmax = fmaxf(fmaxf(sv[0][r], sv[1][r]),
                                   fmaxf(sv[2][r], sv[3][r]));
                #pragma unroll
                for (int off = 1; off < 16; off <<= 1)
                    rmax = fmaxf(rmax, __shfl_xor(rmax, off));
                float mn = fmaxf(m_run[r], rmax);
                float rsum = 0.f;
                #pragma unroll
                for (int sn = 0; sn < 4; ++sn) {
                    float e = __expf(sv[sn][r] - mn);
                    sv[sn][r] = e;
                    rsum += e;
                }
                #pragma unroll
                for (int off = 1; off < 16; off <<= 1)
                    rsum += __shfl_xor(rsum, off);
                alpha[r] = __expf(m_run[r] - mn);
                l_run[r] = l_run[r] * alpha[r] + rsum;
                m_run[r] = mn;
            }

            // ---- P -> LDS (natural [i][j], bf16) ----
            #pragma unroll
            for (int sn = 0; sn < 4; ++sn)
                #pragma unroll
                for (int r = 0; r < 4; ++r)
                    Pst[w][4 * q + r][16 * sn + ln15] = (bf16)sv[sn][r];

            // ---- rescale O^T by alpha(i = ln15) ----
            {
                int srcq = (ln15 >> 2) << 4;
                float a0 = __shfl(alpha[0], srcq), a1 = __shfl(alpha[1], srcq);
                float a2 = __shfl(alpha[2], srcq), a3 = __shfl(alpha[3], srcq);
                int rs = ln15 & 3;
                float ai = rs == 0 ? a0 : rs == 1 ? a1 : rs == 2 ? a2 : a3;
                #pragma unroll
                for (int sd = 0; sd < 4; ++sd)
                    #pragma unroll
                    for (int r2 = 0; r2 < 4; ++r2)
                        O_T[sd][r2] *= ai;
            }

            // ---- O^T += V^T @ P^T ----
            #pragma unroll
            for (int ks = 0; ks < 2; ++ks) {
                bf16x8 pT = *(const bf16x8*)&Pst[w][ln15][32 * ks + 8 * q];
                #pragma unroll
                for (int sd = 0; sd < 4; ++sd) {
                    int rv = 16 * sd + ln15;
                    bf16x8 vf = *(const bf16x8*)&Vs[(rv * 8 + ((4 * ks + q) ^ (rv & 7))) * 8];
                    O_T[sd] = __builtin_amdgcn_mfma_f32_16x16x32_bf16(vf, pT, O_T[sd], 0, 0, 0);
                }
            }
        }

        // ---- epilogue: 1/l(i=ln15), write O^T scattered (once per phase) ----
        {
            int srcq = (ln15 >> 2) << 4;
            float l0 = __shfl(l_run[0], srcq), l1 = __shfl(l_run[1], srcq);
            float l2 = __shfl(l_run[2], srcq), l3 = __shfl(l_run[3], srcq);
            int rs = ln15 & 3;
            float li = rs == 0 ? l0 : rs == 1 ? l1 : rs == 2 ? l2 : l3;
            float inv = 1.0f / li;
            size_t row = (size_t)bi * SEQ_N + i0 + 16 * w + ln15;
            #pragma unroll
            for (int sd = 0; sd < 4; ++sd)
                #pragma unroll
                for (int r = 0; r < 4; ++r)
                    ob[row * DIM + hh * DH + 16 * sd + 4 * q + r] =
                        (bf16)(O_T[sd][r] * inv);
        }
    }
}

// ---------------------------------------------------------------------------
extern "C" void kernel_launch(void* const* d_in, const int* in_sizes, int n_in,
                              void* d_out, int out_size, void* d_ws, size_t ws_size,
                              hipStream_t stream)
{
    const float* x    = (const float*)d_in[0];
    const float* pos  = (const float*)d_in[1];
    const float* Wq   = (const float*)d_in[2];
    const float* bq   = (const float*)d_in[3];
    const float* Wkv  = (const float*)d_in[4];
    const float* bkv  = (const float*)d_in[5];
    const float* Wp   = (const float*)d_in[6];
    const float* bp   = (const float*)d_in[7];
    const float* Wo   = (const float*)d_in[8];
    const float* bo   = (const float*)d_in[9];
    float* out = (float*)d_out;

    const int M = 2 * SEQ_N;   // 4096
    char* ws = (char*)d_ws;
    bf16* xb    = (bf16*)ws;   ws += (size_t)M * DIM * 2;
    bf16* WqT   = (bf16*)ws;   ws += (size_t)DIM * DIM * 2;
    bf16* WkvT  = (bf16*)ws;   ws += (size_t)2 * DIM * DIM * 2;
    bf16* WoT   = (bf16*)ws;   ws += (size_t)DIM * DIM * 2;
    bf16* qbuf  = (bf16*)ws;   ws += (size_t)M * DIM * 2;
    bf16* kbuf  = (bf16*)ws;   ws += (size_t)M * DIM * 2;
    bf16* vtbuf = (bf16*)ws;   ws += (size_t)M * DIM * 2;
    bf16* pfrag = (bf16*)ws;   ws += (size_t)512 * 1024;
    bf16* abuf  = (bf16*)ws;

    dim3 blk(256);
    cast_bf16_kernel<<<dim3(M * DIM / 1024), blk, 0, stream>>>(x, xb, M * DIM);
    transpose_cast_kernel<<<dim3(DIM / 32, DIM / 32), blk, 0, stream>>>(Wq, WqT, DIM, DIM);
    transpose_cast_kernel<<<dim3(2 * DIM / 32, DIM / 32), blk, 0, stream>>>(Wkv, WkvT, DIM, 2 * DIM);
    transpose_cast_kernel<<<dim3(DIM / 32, DIM / 32), blk, 0, stream>>>(Wo, WoT, DIM, DIM);

    mfma_gemm_bt<0><<<dim3(DIM / 128, M / 128), blk, 0, stream>>>(
        xb, WqT, bq, (void*)qbuf, nullptr, M, DIM, DIM);
    mfma_gemm_bt<2><<<dim3(2 * DIM / 128, M / 128), blk, 0, stream>>>(
        xb, WkvT, bkv, (void*)kbuf, vtbuf, M, 2 * DIM, DIM);
    gemm_bias_p_kernel<<<dim3(1, SEQ_N / 64), blk, 0, stream>>>(
        pos, Wp, bp, pfrag, SEQ_N, DH, DIM);

    attn_mfma_kernel<<<dim3(16, 32), blk, 0, stream>>>(
        qbuf, kbuf, vtbuf, pfrag, abuf);

    mfma_gemm_bt<1><<<dim3(DIM / 128, M / 128), blk, 0, stream>>>(
        abuf, WoT, bo, (void*)out, nullptr, M, DIM, DIM);
}

// Round 5
// 301.617 us; speedup vs baseline: 11.1033x; 1.1664x over previous
//
#include <hip/hip_runtime.h>
#include <hip/hip_bf16.h>
#include <cstdint>
#include <cstddef>

#define SEQ_N 2048
#define DIM   1024
#define NHEAD 16
#define DH    64

typedef __bf16 bf16;
typedef __attribute__((ext_vector_type(8))) __bf16 bf16x8;
typedef __attribute__((ext_vector_type(4))) __bf16 bf16x4;
typedef __attribute__((ext_vector_type(4))) float f32x4;

// async global->LDS 16B copy: LDS dest = wave-uniform base + lane*16
__device__ __forceinline__ void gl_lds16(const bf16* g, bf16* l) {
    __builtin_amdgcn_global_load_lds(
        (const __attribute__((address_space(1))) unsigned int*)g,
        (__attribute__((address_space(3))) unsigned int*)l, 16, 0, 0);
}

// ---------------------------------------------------------------------------
// fused cast: xb = bf16(x) [4M elems], posb = bf16(pos) [2M elems]
// grid 6144 x 256 x 4 elems == exactly 6M
// ---------------------------------------------------------------------------
__global__ __launch_bounds__(256) void cast2_kernel(
    const float* __restrict__ x, const float* __restrict__ pos,
    bf16* __restrict__ xb, bf16* __restrict__ posb)
{
    const int NX = 4096 * 1024;
    int i = (blockIdx.x * 256 + threadIdx.x) * 4;
    if (i < NX) {
        float4 v = *(const float4*)&x[i];
        xb[i + 0] = (bf16)v.x; xb[i + 1] = (bf16)v.y;
        xb[i + 2] = (bf16)v.z; xb[i + 3] = (bf16)v.w;
    } else {
        int j = i - NX;
        float4 v = *(const float4*)&pos[j];
        posb[j + 0] = (bf16)v.x; posb[j + 1] = (bf16)v.y;
        posb[j + 2] = (bf16)v.z; posb[j + 3] = (bf16)v.w;
    }
}

// ---------------------------------------------------------------------------
// fused transpose+cast of all weights. All sources have 1024 rows (K), so
// dst K-stride is uniformly 1024. Wq -> WqkvT[0:1024], Wkv -> WqkvT[1024:],
// Wo -> WoT, Wp -> WpT. grid = 1024 + 2048 + 1024 + 64 = 4160 tiles.
// ---------------------------------------------------------------------------
__global__ __launch_bounds__(256) void transpose_all_kernel(
    const float* __restrict__ Wq, const float* __restrict__ Wkv,
    const float* __restrict__ Wo, const float* __restrict__ Wp,
    bf16* __restrict__ WqkvT, bf16* __restrict__ WoT, bf16* __restrict__ WpT)
{
    __shared__ float t[32][33];
    int bid = blockIdx.x;
    const float* src; bf16* dst; int tidx, nx, N;
    if (bid < 1024)      { src = Wq;  dst = WqkvT;                         tidx = bid;        nx = 32; N = 1024; }
    else if (bid < 3072) { src = Wkv; dst = WqkvT + (size_t)1024 * 1024;   tidx = bid - 1024; nx = 64; N = 2048; }
    else if (bid < 4096) { src = Wo;  dst = WoT;                           tidx = bid - 3072; nx = 32; N = 1024; }
    else                 { src = Wp;  dst = WpT;                           tidx = bid - 4096; nx = 2;  N = 64;   }
    int n0 = (tidx % nx) * 32, k0 = (tidx / nx) * 32;
    int tx = threadIdx.x & 31, ty = threadIdx.x >> 5;
    #pragma unroll
    for (int r = ty; r < 32; r += 8)
        t[r][tx] = src[(size_t)(k0 + r) * N + n0 + tx];
    __syncthreads();
    #pragma unroll
    for (int r = ty; r < 32; r += 8)
        dst[(size_t)(n0 + r) * 1024 + k0 + tx] = (bf16)t[tx][r];
}

// ---------------------------------------------------------------------------
// bf16 MFMA GEMM (m97 structure): C[M,N] = A[M,K] @ BT[N,K]^T + bias
// MODE 1: fp32 out. MODE 3: merged qkv: col<1024 -> qbuf (bias=bq),
// col<2048 -> kbuf, else vtbuf transposed (b,h,d,t) (bias=bkv).
// ---------------------------------------------------------------------------
template<int MODE>
__global__ __launch_bounds__(256) void mfma_gemm_bt(
    const bf16* __restrict__ A, const bf16* __restrict__ BT,
    const float* __restrict__ bias, const float* __restrict__ bias2,
    void* __restrict__ C, bf16* __restrict__ qbuf, bf16* __restrict__ kbuf,
    bf16* __restrict__ Vt, int M, int N, int K)
{
    __shared__ bf16 At[128 * 64];
    __shared__ bf16 Bt[128 * 64];
    const int tid = threadIdx.x;
    const int w = tid >> 6, lane = tid & 63;
    const int wm = w >> 1, wn = w & 1;
    const int m0 = blockIdx.y * 128, n0 = blockIdx.x * 128;
    const int lr = lane >> 3, c_log = (lane & 7) ^ lr;
    const int q = lane >> 4, ln15 = lane & 15;

    f32x4 acc[4][4] = {};

    for (int k0 = 0; k0 < K; k0 += 64) {
        __syncthreads();
        #pragma unroll
        for (int t = 0; t < 4; ++t) {
            int r = 32 * w + 8 * t + lr;
            gl_lds16(&A[(size_t)(m0 + r) * K + k0 + c_log * 8],
                     &At[(32 * w + 8 * t) * 64]);
            gl_lds16(&BT[(size_t)(n0 + r) * K + k0 + c_log * 8],
                     &Bt[(32 * w + 8 * t) * 64]);
        }
        __syncthreads();

        bf16x8 af[2][4], bfr[2][4];
        #pragma unroll
        for (int ks = 0; ks < 2; ++ks)
            #pragma unroll
            for (int s = 0; s < 4; ++s) {
                int ra = 64 * wm + 16 * s + ln15;
                af[ks][s]  = *(const bf16x8*)&At[(ra * 8 + ((4 * ks + q) ^ (ra & 7))) * 8];
                int rb = 64 * wn + 16 * s + ln15;
                bfr[ks][s] = *(const bf16x8*)&Bt[(rb * 8 + ((4 * ks + q) ^ (rb & 7))) * 8];
            }
        #pragma unroll
        for (int ks = 0; ks < 2; ++ks)
            #pragma unroll
            for (int si = 0; si < 4; ++si)
                #pragma unroll
                for (int sj = 0; sj < 4; ++sj)
                    acc[si][sj] = __builtin_amdgcn_mfma_f32_16x16x32_bf16(
                        af[ks][si], bfr[ks][sj], acc[si][sj], 0, 0, 0);
    }

    #pragma unroll
    for (int si = 0; si < 4; ++si)
        #pragma unroll
        for (int sj = 0; sj < 4; ++sj)
            #pragma unroll
            for (int r = 0; r < 4; ++r) {
                int row = m0 + 64 * wm + 16 * si + 4 * q + r;
                int col = n0 + 64 * wn + 16 * sj + ln15;
                if (MODE == 1) {
                    ((float*)C)[(size_t)row * N + col] = acc[si][sj][r] + bias[col];
                } else {
                    float v = acc[si][sj][r] +
                              (col < 1024 ? bias[col] : bias2[col - 1024]);
                    if (col < 1024) {
                        qbuf[(size_t)row * 1024 + col] = (bf16)v;
                    } else if (col < 2048) {
                        kbuf[(size_t)row * 1024 + (col - 1024)] = (bf16)v;
                    } else {
                        int c2 = col - 2048, h = c2 >> 6, d = c2 & 63;
                        int b = row >> 11, tt = row & (SEQ_N - 1);
                        Vt[((size_t)((b * NHEAD + h) * DH + d)) * SEQ_N + tt] = (bf16)v;
                    }
                }
            }
}

// ---------------------------------------------------------------------------
// p = pos_emb @ Wp + bp (MFMA), output in A/B-fragment-ready layout:
// pfrag[((sb*2 + ks)*64 + qd*16 + lnp)*8 + e], p-row = 16*sb + lnp,
// d = 32*ks + 8*qd + e. 128-row blocks, grid 16.
// ---------------------------------------------------------------------------
__global__ __launch_bounds__(256) void pgemm_kernel(
    const bf16* __restrict__ posb, const bf16* __restrict__ WpT,
    const float* __restrict__ bp, bf16* __restrict__ pfrag)
{
    __shared__ bf16 At[128 * 64];
    __shared__ bf16 Bt[64 * 64];
    const int tid = threadIdx.x, w = tid >> 6, lane = tid & 63;
    const int q = lane >> 4, ln15 = lane & 15;
    const int lr = lane >> 3, c_log = (lane & 7) ^ lr;
    const int m0 = blockIdx.x * 128;

    f32x4 acc[2][4] = {};

    for (int k0 = 0; k0 < 1024; k0 += 64) {
        __syncthreads();
        #pragma unroll
        for (int t = 0; t < 4; ++t)
            gl_lds16(&posb[(size_t)(m0 + 32 * w + 8 * t + lr) * 1024 + k0 + c_log * 8],
                     &At[(32 * w + 8 * t) * 64]);
        #pragma unroll
        for (int t = 0; t < 2; ++t)
            gl_lds16(&WpT[(size_t)(16 * w + 8 * t + lr) * 1024 + k0 + c_log * 8],
                     &Bt[(16 * w + 8 * t) * 64]);
        __syncthreads();

        bf16x8 bfr[2][4];
        #pragma unroll
        for (int ks = 0; ks < 2; ++ks)
            #pragma unroll
            for (int sn = 0; sn < 4; ++sn) {
                int rb = 16 * sn + ln15;
                bfr[ks][sn] = *(const bf16x8*)&Bt[(rb * 8 + ((4 * ks + q) ^ (rb & 7))) * 8];
            }
        #pragma unroll
        for (int sm = 0; sm < 2; ++sm) {
            int ra = 32 * w + 16 * sm + ln15;
            #pragma unroll
            for (int ks = 0; ks < 2; ++ks) {
                bf16x8 af = *(const bf16x8*)&At[(ra * 8 + ((4 * ks + q) ^ (ra & 7))) * 8];
                #pragma unroll
                for (int sn = 0; sn < 4; ++sn)
                    acc[sm][sn] = __builtin_amdgcn_mfma_f32_16x16x32_bf16(
                        af, bfr[ks][sn], acc[sm][sn], 0, 0, 0);
            }
        }
    }

    #pragma unroll
    for (int sm = 0; sm < 2; ++sm)
        #pragma unroll
        for (int sn = 0; sn < 4; ++sn)
            #pragma unroll
            for (int r = 0; r < 4; ++r) {
                int row = m0 + 32 * w + 16 * sm + 4 * q + r;
                int d = 16 * sn + ln15;
                int sb = row >> 4, lnp = row & 15;
                int ks2 = d >> 5, qd = (d >> 3) & 3, e = d & 7;
                pfrag[(((size_t)sb * 2 + ks2) * 64 + qd * 16 + lnp) * 8 + e] =
                    (bf16)(acc[sm][sn][r] + bp[d]);
            }
}

// ---------------------------------------------------------------------------
// MFMA flash attention, TRANSPOSED scores: S^T = K.Q^T (rows j, cols i=lane).
// Softmax stats live at lane=i (in-register reduce + 2 xor-shuffles), which
// matches the O^T = V^T.P^T PV layout -> no redistribution shuffles.
// Bias: S2^T = Pband.Q^T per 16-row band subtile, 5-subtile register ring
// (4 recomputed/iter), spilled to tiny LDS table S2L[i][c], gathered at
// c = 15 - i + jl (16 scalar b16 reads). Q staging LDS is reused for S2L.
// grid (32, 32): qblk = 31-bx (big first), 1024 blocks = 4/CU.
// ---------------------------------------------------------------------------
__global__ __launch_bounds__(256, 4) void attn_mfma_kernel(
    const bf16* __restrict__ qb,    // [4096][1024]
    const bf16* __restrict__ kb,    // [4096][1024]
    const bf16* __restrict__ vt,    // [(b,h,d)][2048]
    const bf16* __restrict__ pfrag, // fragment-ready p
    bf16* __restrict__ ob)          // [4096][1024]
{
    const int bh = blockIdx.y, bi = bh >> 4, hh = bh & 15;
    const int qblk = 31 - (int)blockIdx.x;
    const int i0 = qblk << 6;
    const int tid = threadIdx.x, w = tid >> 6, lane = tid & 63;
    const int q = lane >> 4, ln15 = lane & 15;
    const int lr = lane >> 3, c_log = (lane & 7) ^ lr;

    // smem (bf16 elems): [0,5376) S2L (4w x 16 x 84; first 4096 double as Qs)
    // [5376,9472) Ks ; [9472,13568) Vs ; [13568,17664) Pst (4w x 16 x 64)
    __shared__ __align__(16) bf16 smem[17664];
    bf16* Qs  = smem;
    bf16* S2L = smem + w * 1344;
    bf16* Ks  = smem + 5376;
    bf16* Vs  = smem + 9472;
    bf16* Pw  = smem + 13568 + w * 1024;

    const bf16* qbase = qb + ((size_t)(bi * SEQ_N + i0)) * DIM + hh * DH;
    const bf16* kbase = kb + ((size_t)bi * SEQ_N) * DIM + hh * DH;
    const bf16* vbase = vt + ((size_t)(bi * NHEAD + hh) * DH) * SEQ_N;

    // stage Q (swizzled 64x64)
    #pragma unroll
    for (int t = 0; t < 2; ++t)
        gl_lds16(qbase + (size_t)(16 * w + 8 * t + lr) * DIM + c_log * 8,
                 &Qs[(16 * w + 8 * t) * 64]);
    __syncthreads();
    bf16x8 qf0, qf1;
    {
        int rq = 16 * w + ln15;
        qf0 = *(const bf16x8*)&Qs[(rq * 8 + ((q    ) ^ (rq & 7))) * 8];
        qf1 = *(const bf16x8*)&Qs[(rq * 8 + ((4 + q) ^ (rq & 7))) * 8];
    }
    __syncthreads();   // all q-frags extracted; S2L region now writable

    const int A0 = 127 - 4 * qblk - w;
    f32x4 s2r4;        // ring carry = subtile A0 + 4*jt
    {
        bf16x8 f0 = *(const bf16x8*)&pfrag[(((size_t)A0 * 2 + 0) * 64 + lane) * 8];
        bf16x8 f1 = *(const bf16x8*)&pfrag[(((size_t)A0 * 2 + 1) * 64 + lane) * 8];
        f32x4 a = {0.f, 0.f, 0.f, 0.f};
        a = __builtin_amdgcn_mfma_f32_16x16x32_bf16(f0, qf0, a, 0, 0, 0);
        a = __builtin_amdgcn_mfma_f32_16x16x32_bf16(f1, qf1, a, 0, 0, 0);
        s2r4 = a;
    }

    float m_run = -1e30f, l_run = 0.f;
    f32x4 O_T[4] = {};

    for (int jt = 0; jt <= qblk; ++jt) {
        const int j0 = jt << 6;

        // band fragments for subtiles s=1..4 (global, L2-hot)
        bf16x8 pfA[4][2];
        #pragma unroll
        for (int s = 1; s <= 4; ++s) {
            int sb = A0 + 4 * jt + s;
            if (sb > 127) sb = 127;   // rows past end are masked anyway
            pfA[s-1][0] = *(const bf16x8*)&pfrag[(((size_t)sb * 2 + 0) * 64 + lane) * 8];
            pfA[s-1][1] = *(const bf16x8*)&pfrag[(((size_t)sb * 2 + 1) * 64 + lane) * 8];
        }
        // stage K/V tiles
        #pragma unroll
        for (int t = 0; t < 2; ++t) {
            int r = 16 * w + 8 * t + lr;
            gl_lds16(kbase + (size_t)(j0 + r) * DIM + c_log * 8,
                     &Ks[(16 * w + 8 * t) * 64]);
            gl_lds16(vbase + (size_t)r * SEQ_N + j0 + c_log * 8,
                     &Vs[(16 * w + 8 * t) * 64]);
        }

        // S2 ring: D[c_loc][i] per subtile
        f32x4 s2r[5];
        s2r[0] = s2r4;
        #pragma unroll
        for (int s = 1; s <= 4; ++s) {
            f32x4 a = {0.f, 0.f, 0.f, 0.f};
            a = __builtin_amdgcn_mfma_f32_16x16x32_bf16(pfA[s-1][0], qf0, a, 0, 0, 0);
            a = __builtin_amdgcn_mfma_f32_16x16x32_bf16(pfA[s-1][1], qf1, a, 0, 0, 0);
            s2r[s] = a;
        }
        s2r4 = s2r[4];
        // spill to S2L[i=ln15][c = 16s + 4q + r]
        #pragma unroll
        for (int s = 0; s < 5; ++s)
            #pragma unroll
            for (int r = 0; r < 4; ++r)
                S2L[ln15 * 84 + 16 * s + 4 * q + r] = (bf16)s2r[s][r];

        __syncthreads();   // staging done + S2L visible

        // S1^T = K.Q^T ; add bias, scale, (mask on diag tile)
        float sv[4][4];
        #pragma unroll
        for (int sn = 0; sn < 4; ++sn) {
            int rk = 16 * sn + ln15;
            bf16x8 k0f = *(const bf16x8*)&Ks[(rk * 8 + ((q    ) ^ (rk & 7))) * 8];
            bf16x8 k1f = *(const bf16x8*)&Ks[(rk * 8 + ((4 + q) ^ (rk & 7))) * 8];
            f32x4 a = {0.f, 0.f, 0.f, 0.f};
            a = __builtin_amdgcn_mfma_f32_16x16x32_bf16(k0f, qf0, a, 0, 0, 0);
            a = __builtin_amdgcn_mfma_f32_16x16x32_bf16(k1f, qf1, a, 0, 0, 0);
            #pragma unroll
            for (int r = 0; r < 4; ++r) {
                int jl = 16 * sn + 4 * q + r;
                float b = (float)S2L[ln15 * 84 + 15 - ln15 + jl];
                sv[sn][r] = (a[r] + b) * 0.125f;
            }
        }
        if (jt == qblk) {
            #pragma unroll
            for (int sn = 0; sn < 4; ++sn)
                #pragma unroll
                for (int r = 0; r < 4; ++r)
                    if (16 * sn + 4 * q + r > 16 * w + ln15)
                        sv[sn][r] = -1e30f;
        }

        // online softmax, stats per lane (i = ln15, replicated over quads)
        float mx = sv[0][0];
        #pragma unroll
        for (int sn = 0; sn < 4; ++sn)
            #pragma unroll
            for (int r = 0; r < 4; ++r)
                mx = fmaxf(mx, sv[sn][r]);
        mx = fmaxf(mx, __shfl_xor(mx, 16));
        mx = fmaxf(mx, __shfl_xor(mx, 32));
        const float mn = fmaxf(m_run, mx);
        float sum = 0.f;
        #pragma unroll
        for (int sn = 0; sn < 4; ++sn)
            #pragma unroll
            for (int r = 0; r < 4; ++r) {
                float e = __expf(sv[sn][r] - mn);
                sv[sn][r] = e;
                sum += e;
            }
        sum += __shfl_xor(sum, 16);
        sum += __shfl_xor(sum, 32);
        const float alpha = __expf(m_run - mn);
        l_run = l_run * alpha + sum;
        m_run = mn;

        // P -> per-wave LDS [i][j], chunk-xor swizzled
        #pragma unroll
        for (int sn = 0; sn < 4; ++sn)
            #pragma unroll
            for (int r = 0; r < 4; ++r) {
                int chunk = (2 * sn + (q >> 1)) ^ (ln15 & 7);
                Pw[ln15 * 64 + chunk * 8 + 4 * (q & 1) + r] = (bf16)sv[sn][r];
            }
        // rescale O^T (lane already holds alpha for its i)
        #pragma unroll
        for (int sd = 0; sd < 4; ++sd)
            #pragma unroll
            for (int r = 0; r < 4; ++r)
                O_T[sd][r] *= alpha;

        __builtin_amdgcn_s_waitcnt(0);   // Pw stores visible intra-wave

        // O^T += V^T @ P^T
        #pragma unroll
        for (int ks = 0; ks < 2; ++ks) {
            bf16x8 pT = *(const bf16x8*)&Pw[ln15 * 64 + (((4 * ks + q) ^ (ln15 & 7))) * 8];
            #pragma unroll
            for (int sd = 0; sd < 4; ++sd) {
                int rv = 16 * sd + ln15;
                bf16x8 vf = *(const bf16x8*)&Vs[(rv * 8 + ((4 * ks + q) ^ (rv & 7))) * 8];
                O_T[sd] = __builtin_amdgcn_mfma_f32_16x16x32_bf16(vf, pT, O_T[sd], 0, 0, 0);
            }
        }
        __syncthreads();   // Ks/Vs/S2L consumed; next iter may overwrite
    }

    // epilogue: O^T[d = 16sd+4q+r][i = ln15] / l -> ob[i][d], 8B packed stores
    const float inv = 1.0f / l_run;
    const size_t row = (size_t)bi * SEQ_N + i0 + 16 * w + ln15;
    #pragma unroll
    for (int sd = 0; sd < 4; ++sd) {
        bf16x4 o4;
        #pragma unroll
        for (int r = 0; r < 4; ++r)
            o4[r] = (bf16)(O_T[sd][r] * inv);
        *(bf16x4*)&ob[row * DIM + hh * DH + 16 * sd + 4 * q] = o4;
    }
}

// ---------------------------------------------------------------------------
extern "C" void kernel_launch(void* const* d_in, const int* in_sizes, int n_in,
                              void* d_out, int out_size, void* d_ws, size_t ws_size,
                              hipStream_t stream)
{
    const float* x    = (const float*)d_in[0];
    const float* pos  = (const float*)d_in[1];
    const float* Wq   = (const float*)d_in[2];
    const float* bq   = (const float*)d_in[3];
    const float* Wkv  = (const float*)d_in[4];
    const float* bkv  = (const float*)d_in[5];
    const float* Wp   = (const float*)d_in[6];
    const float* bp   = (const float*)d_in[7];
    const float* Wo   = (const float*)d_in[8];
    const float* bo   = (const float*)d_in[9];
    float* out = (float*)d_out;

    const int M = 2 * SEQ_N;   // 4096
    char* ws = (char*)d_ws;
    bf16* xb     = (bf16*)ws;  ws += (size_t)M * DIM * 2;            // 8MB
    bf16* posb   = (bf16*)ws;  ws += (size_t)SEQ_N * DIM * 2;        // 4MB
    bf16* WqkvT  = (bf16*)ws;  ws += (size_t)3072 * 1024 * 2;        // 6MB
    bf16* WoT    = (bf16*)ws;  ws += (size_t)DIM * DIM * 2;          // 2MB
    bf16* WpT    = (bf16*)ws;  ws += (size_t)DH * DIM * 2;           // 128KB
    bf16* qbuf   = (bf16*)ws;  ws += (size_t)M * DIM * 2;            // 8MB
    bf16* kbuf   = (bf16*)ws;  ws += (size_t)M * DIM * 2;            // 8MB
    bf16* vtbuf  = (bf16*)ws;  ws += (size_t)M * DIM * 2;            // 8MB
    bf16* pfrag  = (bf16*)ws;  ws += (size_t)512 * 1024;             // 512KB (256 used)
    bf16* abuf   = (bf16*)ws;                                        // 8MB

    dim3 blk(256);
    cast2_kernel<<<dim3(6144), blk, 0, stream>>>(x, pos, xb, posb);
    transpose_all_kernel<<<dim3(4160), blk, 0, stream>>>(
        Wq, Wkv, Wo, Wp, WqkvT, WoT, WpT);

    // merged q/k/v projection: N = 3072, 768 blocks (3/CU)
    mfma_gemm_bt<3><<<dim3(24, 32), blk, 0, stream>>>(
        xb, WqkvT, bq, bkv, nullptr, qbuf, kbuf, vtbuf, M, 3072, DIM);

    // p projection (fragment-ready output)
    pgemm_kernel<<<dim3(16), blk, 0, stream>>>(posb, WpT, bp, pfrag);

    // attention core
    attn_mfma_kernel<<<dim3(32, 32), blk, 0, stream>>>(
        qbuf, kbuf, vtbuf, pfrag, abuf);

    // output projection (fp32 out)
    mfma_gemm_bt<1><<<dim3(8, 32), blk, 0, stream>>>(
        abuf, WoT, bo, nullptr, (void*)out, nullptr, nullptr, nullptr, M, DIM, DIM);
}

// Round 6
// 246.036 us; speedup vs baseline: 13.6117x; 1.2259x over previous
//
#include <hip/hip_runtime.h>
#include <hip/hip_bf16.h>
#include <cstdint>
#include <cstddef>

#define SEQ_N 2048
#define DIM   1024
#define NHEAD 16
#define DH    64

typedef __bf16 bf16;
typedef __attribute__((ext_vector_type(8))) __bf16 bf16x8;
typedef __attribute__((ext_vector_type(4))) __bf16 bf16x4;
typedef __attribute__((ext_vector_type(4))) float f32x4;

// async global->LDS 16B copy: LDS dest = wave-uniform base + lane*16
__device__ __forceinline__ void gl_lds16(const bf16* g, bf16* l) {
    __builtin_amdgcn_global_load_lds(
        (const __attribute__((address_space(1))) unsigned int*)g,
        (__attribute__((address_space(3))) unsigned int*)l, 16, 0, 0);
}

// ---------------------------------------------------------------------------
// prep: fused input cast (x, pos -> bf16) + all weight transposes.
// blocks [0,6144): cast 1024 elems each (4M x + 2M pos).
// blocks [6144,10304): 32x32 transpose tiles (Wq|Wkv -> WqkvT, Wo, Wp).
// ---------------------------------------------------------------------------
__global__ __launch_bounds__(256) void prep_kernel(
    const float* __restrict__ x, const float* __restrict__ pos,
    const float* __restrict__ Wq, const float* __restrict__ Wkv,
    const float* __restrict__ Wo, const float* __restrict__ Wp,
    bf16* __restrict__ xb, bf16* __restrict__ posb,
    bf16* __restrict__ WqkvT, bf16* __restrict__ WoT, bf16* __restrict__ WpT)
{
    int bid = blockIdx.x;
    if (bid < 6144) {
        const int NX = 4096 * 1024;
        int i = (bid * 256 + threadIdx.x) * 4;
        if (i < NX) {
            float4 v = *(const float4*)&x[i];
            xb[i + 0] = (bf16)v.x; xb[i + 1] = (bf16)v.y;
            xb[i + 2] = (bf16)v.z; xb[i + 3] = (bf16)v.w;
        } else {
            int j = i - NX;
            float4 v = *(const float4*)&pos[j];
            posb[j + 0] = (bf16)v.x; posb[j + 1] = (bf16)v.y;
            posb[j + 2] = (bf16)v.z; posb[j + 3] = (bf16)v.w;
        }
        return;
    }
    __shared__ float t[32][33];
    bid -= 6144;
    const float* src; bf16* dst; int tidx, nx, N;
    if (bid < 1024)      { src = Wq;  dst = WqkvT;                       tidx = bid;        nx = 32; N = 1024; }
    else if (bid < 3072) { src = Wkv; dst = WqkvT + (size_t)1024 * 1024; tidx = bid - 1024; nx = 64; N = 2048; }
    else if (bid < 4096) { src = Wo;  dst = WoT;                         tidx = bid - 3072; nx = 32; N = 1024; }
    else                 { src = Wp;  dst = WpT;                         tidx = bid - 4096; nx = 2;  N = 64;   }
    int n0 = (tidx % nx) * 32, k0 = (tidx / nx) * 32;
    int tx = threadIdx.x & 31, ty = threadIdx.x >> 5;
    #pragma unroll
    for (int r = ty; r < 32; r += 8)
        t[r][tx] = src[(size_t)(k0 + r) * N + n0 + tx];
    __syncthreads();
    #pragma unroll
    for (int r = ty; r < 32; r += 8)
        dst[(size_t)(n0 + r) * 1024 + k0 + tx] = (bf16)t[tx][r];
}

// ---------------------------------------------------------------------------
// qkv projection + p projection, one dispatch. grid (25, 32).
// bx in [0,24): 128x128 tile of [q|k|v] = xb @ WqkvT^T + bias.
//   bx<16 -> q/k natural layout; bx>=16 -> V transposed (b,h,d,t) via an
//   LDS bounce so global stores are 16B vectors over contiguous t.
// bx==24 (by<16): p = posb @ WpT^T + bp in fragment-ready layout.
// ---------------------------------------------------------------------------
__global__ __launch_bounds__(256) void qkvp_kernel(
    const bf16* __restrict__ xb, const bf16* __restrict__ WqkvT,
    const bf16* __restrict__ posb, const bf16* __restrict__ WpT,
    const float* __restrict__ bq, const float* __restrict__ bkv,
    const float* __restrict__ bp,
    bf16* __restrict__ qbuf, bf16* __restrict__ kbuf,
    bf16* __restrict__ vtbuf, bf16* __restrict__ pfrag)
{
    __shared__ __align__(16) bf16 sm[128 * 132];   // At|Bt staging / V bounce
    bf16* At = sm;
    bf16* Bt = sm + 128 * 64;
    const int tid = threadIdx.x, w = tid >> 6, lane = tid & 63;
    const int q = lane >> 4, ln15 = lane & 15;
    const int lr = lane >> 3, c_log = (lane & 7) ^ lr;
    const int bx = blockIdx.x, by = blockIdx.y;
    const int m0 = by * 128;

    if (bx == 24) {
        if (by >= 16) return;
        f32x4 acc[2][4] = {};
        for (int k0 = 0; k0 < 1024; k0 += 64) {
            __syncthreads();
            #pragma unroll
            for (int t = 0; t < 4; ++t)
                gl_lds16(&posb[(size_t)(m0 + 32 * w + 8 * t + lr) * 1024 + k0 + c_log * 8],
                         &At[(32 * w + 8 * t) * 64]);
            #pragma unroll
            for (int t = 0; t < 2; ++t)
                gl_lds16(&WpT[(size_t)(16 * w + 8 * t + lr) * 1024 + k0 + c_log * 8],
                         &Bt[(16 * w + 8 * t) * 64]);
            __syncthreads();
            bf16x8 bfr[2][4];
            #pragma unroll
            for (int ks = 0; ks < 2; ++ks)
                #pragma unroll
                for (int sn = 0; sn < 4; ++sn) {
                    int rb = 16 * sn + ln15;
                    bfr[ks][sn] = *(const bf16x8*)&Bt[(rb * 8 + ((4 * ks + q) ^ (rb & 7))) * 8];
                }
            #pragma unroll
            for (int sm2 = 0; sm2 < 2; ++sm2) {
                int ra = 32 * w + 16 * sm2 + ln15;
                #pragma unroll
                for (int ks = 0; ks < 2; ++ks) {
                    bf16x8 af = *(const bf16x8*)&At[(ra * 8 + ((4 * ks + q) ^ (ra & 7))) * 8];
                    #pragma unroll
                    for (int sn = 0; sn < 4; ++sn)
                        acc[sm2][sn] = __builtin_amdgcn_mfma_f32_16x16x32_bf16(
                            af, bfr[ks][sn], acc[sm2][sn], 0, 0, 0);
                }
            }
        }
        #pragma unroll
        for (int sm2 = 0; sm2 < 2; ++sm2)
            #pragma unroll
            for (int sn = 0; sn < 4; ++sn)
                #pragma unroll
                for (int r = 0; r < 4; ++r) {
                    int row = m0 + 32 * w + 16 * sm2 + 4 * q + r;
                    int d = 16 * sn + ln15;
                    int sb = row >> 4, lnp = row & 15;
                    int ks2 = d >> 5, qd = (d >> 3) & 3, e = d & 7;
                    pfrag[(((size_t)sb * 2 + ks2) * 64 + qd * 16 + lnp) * 8 + e] =
                        (bf16)(acc[sm2][sn][r] + bp[d]);
                }
        return;
    }

    // ---- qkv GEMM tile ----
    const int n0 = bx * 128;
    const int wm = w >> 1, wn = w & 1;
    f32x4 acc[4][4] = {};

    for (int k0 = 0; k0 < 1024; k0 += 64) {
        __syncthreads();
        #pragma unroll
        for (int t = 0; t < 4; ++t) {
            int r = 32 * w + 8 * t + lr;
            gl_lds16(&xb[(size_t)(m0 + r) * 1024 + k0 + c_log * 8],
                     &At[(32 * w + 8 * t) * 64]);
            gl_lds16(&WqkvT[(size_t)(n0 + r) * 1024 + k0 + c_log * 8],
                     &Bt[(32 * w + 8 * t) * 64]);
        }
        __syncthreads();

        bf16x8 af[2][4], bfr[2][4];
        #pragma unroll
        for (int ks = 0; ks < 2; ++ks)
            #pragma unroll
            for (int s = 0; s < 4; ++s) {
                int ra = 64 * wm + 16 * s + ln15;
                af[ks][s]  = *(const bf16x8*)&At[(ra * 8 + ((4 * ks + q) ^ (ra & 7))) * 8];
                int rb = 64 * wn + 16 * s + ln15;
                bfr[ks][s] = *(const bf16x8*)&Bt[(rb * 8 + ((4 * ks + q) ^ (rb & 7))) * 8];
            }
        #pragma unroll
        for (int ks = 0; ks < 2; ++ks)
            #pragma unroll
            for (int si = 0; si < 4; ++si)
                #pragma unroll
                for (int sj = 0; sj < 4; ++sj)
                    acc[si][sj] = __builtin_amdgcn_mfma_f32_16x16x32_bf16(
                        af[ks][si], bfr[ks][sj], acc[si][sj], 0, 0, 0);
    }

    if (bx < 16) {
        // q / k natural layout
        #pragma unroll
        for (int si = 0; si < 4; ++si)
            #pragma unroll
            for (int sj = 0; sj < 4; ++sj)
                #pragma unroll
                for (int r = 0; r < 4; ++r) {
                    int row = m0 + 64 * wm + 16 * si + 4 * q + r;
                    int col = n0 + 64 * wn + 16 * sj + ln15;
                    float v = acc[si][sj][r] + (col < 1024 ? bq[col] : bkv[col - 1024]);
                    if (col < 1024) qbuf[(size_t)row * 1024 + col] = (bf16)v;
                    else            kbuf[(size_t)row * 1024 + (col - 1024)] = (bf16)v;
                }
    } else {
        // V: transpose to (b,h,d,t) via LDS bounce, 16B coalesced stores
        __syncthreads();   // all waves done reading At/Bt
        #pragma unroll
        for (int si = 0; si < 4; ++si)
            #pragma unroll
            for (int sj = 0; sj < 4; ++sj) {
                int dL = 64 * wn + 16 * sj + ln15;        // 0..127
                int tL = 64 * wm + 16 * si + 4 * q;       // +r
                float bias = bkv[1024 + (bx - 16) * 128 + dL];
                bf16x4 o4;
                #pragma unroll
                for (int r = 0; r < 4; ++r)
                    o4[r] = (bf16)(acc[si][sj][r] + bias);
                *(bf16x4*)&sm[dL * 132 + tL] = o4;
            }
        __syncthreads();
        const int b = m0 >> 11;
        const int t0 = m0 & 2047;
        const int h0 = (bx - 16) * 2;
        #pragma unroll
        for (int p = 0; p < 16; ++p) {
            int d = (tid >> 5) + 8 * p;
            int t = (tid & 31) * 4;
            bf16x4 v4 = *(const bf16x4*)&sm[d * 132 + t];
            int rowv = (b * NHEAD + h0 + (d >> 6)) * DH + (d & 63);
            *(bf16x4*)&vtbuf[(size_t)rowv * SEQ_N + t0 + t] = v4;
        }
    }
}

// ---------------------------------------------------------------------------
// MFMA flash attention, transposed scores S^T = K.Q^T (stats at lane=i),
// O^T = V^T.P^T, register S2 ring + tiny LDS bias table.
// Balance: qblk = ((by>>3)&1) ? 31-bx : bx  -> each CU's 4 resident blocks
// (same bx, by step 8 under linear round-robin) sum to exactly 66 iters.
// ---------------------------------------------------------------------------
__global__ __launch_bounds__(256, 4) void attn_mfma_kernel(
    const bf16* __restrict__ qb,    // [4096][1024]
    const bf16* __restrict__ kb,    // [4096][1024]
    const bf16* __restrict__ vt,    // [(b,h,d)][2048]
    const bf16* __restrict__ pfrag, // fragment-ready p
    bf16* __restrict__ ob)          // [4096][1024]
{
    const int bh = blockIdx.y, bi = bh >> 4, hh = bh & 15;
    const int qblk = ((blockIdx.y >> 3) & 1) ? (31 - (int)blockIdx.x)
                                             : (int)blockIdx.x;
    const int i0 = qblk << 6;
    const int tid = threadIdx.x, w = tid >> 6, lane = tid & 63;
    const int q = lane >> 4, ln15 = lane & 15;
    const int lr = lane >> 3, c_log = (lane & 7) ^ lr;

    __shared__ __align__(16) bf16 smem[17664];
    bf16* Qs  = smem;                    // 64x64 staging (reused as S2L)
    bf16* S2L = smem + w * 1344;         // per-wave 16 x 84
    bf16* Ks  = smem + 5376;
    bf16* Vs  = smem + 9472;
    bf16* Pw  = smem + 13568 + w * 1024;

    const bf16* qbase = qb + ((size_t)(bi * SEQ_N + i0)) * DIM + hh * DH;
    const bf16* kbase = kb + ((size_t)bi * SEQ_N) * DIM + hh * DH;
    const bf16* vbase = vt + ((size_t)(bi * NHEAD + hh) * DH) * SEQ_N;

    #pragma unroll
    for (int t = 0; t < 2; ++t)
        gl_lds16(qbase + (size_t)(16 * w + 8 * t + lr) * DIM + c_log * 8,
                 &Qs[(16 * w + 8 * t) * 64]);
    __syncthreads();
    bf16x8 qf0, qf1;
    {
        int rq = 16 * w + ln15;
        qf0 = *(const bf16x8*)&Qs[(rq * 8 + ((q    ) ^ (rq & 7))) * 8];
        qf1 = *(const bf16x8*)&Qs[(rq * 8 + ((4 + q) ^ (rq & 7))) * 8];
    }
    __syncthreads();   // q-frags extracted; S2L region now writable

    const int A0 = 127 - 4 * qblk - w;
    f32x4 s2r4;
    {
        bf16x8 f0 = *(const bf16x8*)&pfrag[(((size_t)A0 * 2 + 0) * 64 + lane) * 8];
        bf16x8 f1 = *(const bf16x8*)&pfrag[(((size_t)A0 * 2 + 1) * 64 + lane) * 8];
        f32x4 a = {0.f, 0.f, 0.f, 0.f};
        a = __builtin_amdgcn_mfma_f32_16x16x32_bf16(f0, qf0, a, 0, 0, 0);
        a = __builtin_amdgcn_mfma_f32_16x16x32_bf16(f1, qf1, a, 0, 0, 0);
        s2r4 = a;
    }

    float m_run = -1e30f, l_run = 0.f;
    f32x4 O_T[4] = {};

    for (int jt = 0; jt <= qblk; ++jt) {
        const int j0 = jt << 6;

        bf16x8 pfA[4][2];
        #pragma unroll
        for (int s = 1; s <= 4; ++s) {
            int sb = A0 + 4 * jt + s;
            if (sb > 127) sb = 127;
            pfA[s-1][0] = *(const bf16x8*)&pfrag[(((size_t)sb * 2 + 0) * 64 + lane) * 8];
            pfA[s-1][1] = *(const bf16x8*)&pfrag[(((size_t)sb * 2 + 1) * 64 + lane) * 8];
        }
        #pragma unroll
        for (int t = 0; t < 2; ++t) {
            int r = 16 * w + 8 * t + lr;
            gl_lds16(kbase + (size_t)(j0 + r) * DIM + c_log * 8,
                     &Ks[(16 * w + 8 * t) * 64]);
            gl_lds16(vbase + (size_t)r * SEQ_N + j0 + c_log * 8,
                     &Vs[(16 * w + 8 * t) * 64]);
        }

        f32x4 s2r[5];
        s2r[0] = s2r4;
        #pragma unroll
        for (int s = 1; s <= 4; ++s) {
            f32x4 a = {0.f, 0.f, 0.f, 0.f};
            a = __builtin_amdgcn_mfma_f32_16x16x32_bf16(pfA[s-1][0], qf0, a, 0, 0, 0);
            a = __builtin_amdgcn_mfma_f32_16x16x32_bf16(pfA[s-1][1], qf1, a, 0, 0, 0);
            s2r[s] = a;
        }
        s2r4 = s2r[4];
        #pragma unroll
        for (int s = 0; s < 5; ++s)
            #pragma unroll
            for (int r = 0; r < 4; ++r)
                S2L[ln15 * 84 + 16 * s + 4 * q + r] = (bf16)s2r[s][r];

        __syncthreads();

        float sv[4][4];
        #pragma unroll
        for (int sn = 0; sn < 4; ++sn) {
            int rk = 16 * sn + ln15;
            bf16x8 k0f = *(const bf16x8*)&Ks[(rk * 8 + ((q    ) ^ (rk & 7))) * 8];
            bf16x8 k1f = *(const bf16x8*)&Ks[(rk * 8 + ((4 + q) ^ (rk & 7))) * 8];
            f32x4 a = {0.f, 0.f, 0.f, 0.f};
            a = __builtin_amdgcn_mfma_f32_16x16x32_bf16(k0f, qf0, a, 0, 0, 0);
            a = __builtin_amdgcn_mfma_f32_16x16x32_bf16(k1f, qf1, a, 0, 0, 0);
            #pragma unroll
            for (int r = 0; r < 4; ++r) {
                int jl = 16 * sn + 4 * q + r;
                float b = (float)S2L[ln15 * 84 + 15 - ln15 + jl];
                sv[sn][r] = (a[r] + b) * 0.125f;
            }
        }
        if (jt == qblk) {
            #pragma unroll
            for (int sn = 0; sn < 4; ++sn)
                #pragma unroll
                for (int r = 0; r < 4; ++r)
                    if (16 * sn + 4 * q + r > 16 * w + ln15)
                        sv[sn][r] = -1e30f;
        }

        float mx = sv[0][0];
        #pragma unroll
        for (int sn = 0; sn < 4; ++sn)
            #pragma unroll
            for (int r = 0; r < 4; ++r)
                mx = fmaxf(mx, sv[sn][r]);
        mx = fmaxf(mx, __shfl_xor(mx, 16));
        mx = fmaxf(mx, __shfl_xor(mx, 32));
        const float mn = fmaxf(m_run, mx);
        float sum = 0.f;
        #pragma unroll
        for (int sn = 0; sn < 4; ++sn)
            #pragma unroll
            for (int r = 0; r < 4; ++r) {
                float e = __expf(sv[sn][r] - mn);
                sv[sn][r] = e;
                sum += e;
            }
        sum += __shfl_xor(sum, 16);
        sum += __shfl_xor(sum, 32);
        const float alpha = __expf(m_run - mn);
        l_run = l_run * alpha + sum;
        m_run = mn;

        #pragma unroll
        for (int sn = 0; sn < 4; ++sn)
            #pragma unroll
            for (int r = 0; r < 4; ++r) {
                int chunk = (2 * sn + (q >> 1)) ^ (ln15 & 7);
                Pw[ln15 * 64 + chunk * 8 + 4 * (q & 1) + r] = (bf16)sv[sn][r];
            }
        #pragma unroll
        for (int sd = 0; sd < 4; ++sd)
            #pragma unroll
            for (int r = 0; r < 4; ++r)
                O_T[sd][r] *= alpha;

        __builtin_amdgcn_s_waitcnt(0);

        #pragma unroll
        for (int ks = 0; ks < 2; ++ks) {
            bf16x8 pT = *(const bf16x8*)&Pw[ln15 * 64 + (((4 * ks + q) ^ (ln15 & 7))) * 8];
            #pragma unroll
            for (int sd = 0; sd < 4; ++sd) {
                int rv = 16 * sd + ln15;
                bf16x8 vf = *(const bf16x8*)&Vs[(rv * 8 + ((4 * ks + q) ^ (rv & 7))) * 8];
                O_T[sd] = __builtin_amdgcn_mfma_f32_16x16x32_bf16(vf, pT, O_T[sd], 0, 0, 0);
            }
        }
        __syncthreads();
    }

    const float inv = 1.0f / l_run;
    const size_t row = (size_t)bi * SEQ_N + i0 + 16 * w + ln15;
    #pragma unroll
    for (int sd = 0; sd < 4; ++sd) {
        bf16x4 o4;
        #pragma unroll
        for (int r = 0; r < 4; ++r)
            o4[r] = (bf16)(O_T[sd][r] * inv);
        *(bf16x4*)&ob[row * DIM + hh * DH + 16 * sd + 4 * q] = o4;
    }
}

// ---------------------------------------------------------------------------
// out = abuf @ WoT^T + bo, fp32 out. 128x64 tiles -> grid (16,32), 2/CU.
// ---------------------------------------------------------------------------
__global__ __launch_bounds__(256) void outproj_kernel(
    const bf16* __restrict__ ab, const bf16* __restrict__ WoT,
    const float* __restrict__ bo, float* __restrict__ out)
{
    __shared__ __align__(16) bf16 At[128 * 64];
    __shared__ __align__(16) bf16 Bt[64 * 64];
    const int tid = threadIdx.x, w = tid >> 6, lane = tid & 63;
    const int q = lane >> 4, ln15 = lane & 15;
    const int lr = lane >> 3, c_log = (lane & 7) ^ lr;
    const int m0 = blockIdx.y * 128, n0 = blockIdx.x * 64;

    f32x4 acc[2][4] = {};
    for (int k0 = 0; k0 < 1024; k0 += 64) {
        __syncthreads();
        #pragma unroll
        for (int t = 0; t < 4; ++t)
            gl_lds16(&ab[(size_t)(m0 + 32 * w + 8 * t + lr) * 1024 + k0 + c_log * 8],
                     &At[(32 * w + 8 * t) * 64]);
        #pragma unroll
        for (int t = 0; t < 2; ++t)
            gl_lds16(&WoT[(size_t)(n0 + 16 * w + 8 * t + lr) * 1024 + k0 + c_log * 8],
                     &Bt[(16 * w + 8 * t) * 64]);
        __syncthreads();

        bf16x8 bfr[2][4];
        #pragma unroll
        for (int ks = 0; ks < 2; ++ks)
            #pragma unroll
            for (int sn = 0; sn < 4; ++sn) {
                int rb = 16 * sn + ln15;
                bfr[ks][sn] = *(const bf16x8*)&Bt[(rb * 8 + ((4 * ks + q) ^ (rb & 7))) * 8];
            }
        #pragma unroll
        for (int sm2 = 0; sm2 < 2; ++sm2) {
            int ra = 32 * w + 16 * sm2 + ln15;
            #pragma unroll
            for (int ks = 0; ks < 2; ++ks) {
                bf16x8 af = *(const bf16x8*)&At[(ra * 8 + ((4 * ks + q) ^ (ra & 7))) * 8];
                #pragma unroll
                for (int sn = 0; sn < 4; ++sn)
                    acc[sm2][sn] = __builtin_amdgcn_mfma_f32_16x16x32_bf16(
                        af, bfr[ks][sn], acc[sm2][sn], 0, 0, 0);
            }
        }
    }
    #pragma unroll
    for (int sm2 = 0; sm2 < 2; ++sm2)
        #pragma unroll
        for (int sn = 0; sn < 4; ++sn) {
            int col = n0 + 16 * sn + ln15;
            float bias = bo[col];
            #pragma unroll
            for (int r = 0; r < 4; ++r) {
                int row = m0 + 32 * w + 16 * sm2 + 4 * q + r;
                out[(size_t)row * 1024 + col] = acc[sm2][sn][r] + bias;
            }
        }
}

// ---------------------------------------------------------------------------
extern "C" void kernel_launch(void* const* d_in, const int* in_sizes, int n_in,
                              void* d_out, int out_size, void* d_ws, size_t ws_size,
                              hipStream_t stream)
{
    const float* x    = (const float*)d_in[0];
    const float* pos  = (const float*)d_in[1];
    const float* Wq   = (const float*)d_in[2];
    const float* bq   = (const float*)d_in[3];
    const float* Wkv  = (const float*)d_in[4];
    const float* bkv  = (const float*)d_in[5];
    const float* Wp   = (const float*)d_in[6];
    const float* bp   = (const float*)d_in[7];
    const float* Wo   = (const float*)d_in[8];
    const float* bo   = (const float*)d_in[9];
    float* out = (float*)d_out;

    const int M = 2 * SEQ_N;   // 4096
    char* ws = (char*)d_ws;
    bf16* xb     = (bf16*)ws;  ws += (size_t)M * DIM * 2;
    bf16* posb   = (bf16*)ws;  ws += (size_t)SEQ_N * DIM * 2;
    bf16* WqkvT  = (bf16*)ws;  ws += (size_t)3072 * 1024 * 2;
    bf16* WoT    = (bf16*)ws;  ws += (size_t)DIM * DIM * 2;
    bf16* WpT    = (bf16*)ws;  ws += (size_t)DH * DIM * 2;
    bf16* qbuf   = (bf16*)ws;  ws += (size_t)M * DIM * 2;
    bf16* kbuf   = (bf16*)ws;  ws += (size_t)M * DIM * 2;
    bf16* vtbuf  = (bf16*)ws;  ws += (size_t)M * DIM * 2;
    bf16* pfrag  = (bf16*)ws;  ws += (size_t)512 * 1024;
    bf16* abuf   = (bf16*)ws;

    dim3 blk(256);
    prep_kernel<<<dim3(10304), blk, 0, stream>>>(
        x, pos, Wq, Wkv, Wo, Wp, xb, posb, WqkvT, WoT, WpT);

    qkvp_kernel<<<dim3(25, 32), blk, 0, stream>>>(
        xb, WqkvT, posb, WpT, bq, bkv, bp, qbuf, kbuf, vtbuf, pfrag);

    attn_mfma_kernel<<<dim3(32, 32), blk, 0, stream>>>(
        qbuf, kbuf, vtbuf, pfrag, abuf);

    outproj_kernel<<<dim3(16, 32), blk, 0, stream>>>(
        abuf, WoT, bo, out);
}